// Round 8
// baseline (1130.965 us; speedup 1.0000x reference)
//
#include <hip/hip_runtime.h>
#include <math.h>

#define HDIM 128
#define NGAUSS 50
#define NLAYER 6
#define TSTR 136   // LDS bf16 tile row stride (shorts); %8==0 keeps ds_read_b128 aligned
#define VSTR 132   // LDS f32 tile row stride (floats)

typedef unsigned short ushortT;
typedef __attribute__((ext_vector_type(8))) short bf16x8;
typedef __attribute__((ext_vector_type(4))) float f32x4;

static __device__ __forceinline__ float bf2f(unsigned short u){
  union { unsigned int i; float f; } x; x.i = ((unsigned int)u) << 16; return x.f;
}
static __device__ __forceinline__ unsigned short f2bf(float f){
  union { float f; unsigned int i; } x; x.f = f;
  unsigned int i = x.i;
  unsigned int r = (i + 0x7FFFu + ((i >> 16) & 1u)) >> 16;
  return (unsigned short)r;
}
// softplus(x) - log(2), numerically stable
static __device__ __forceinline__ float ssp(float x){
  float sp = fmaxf(x, 0.0f) + log1pf(expf(-fabsf(x)));
  return sp - 0.69314718055994530942f;
}

// ---------------- CSR build ----------------
__global__ void k_count(const int* __restrict__ row, int* __restrict__ counts, int E){
  int e = blockIdx.x * 256 + threadIdx.x;
  if (e < E) atomicAdd(&counts[row[e]], 1);
}

__global__ void k_scan1(const int* __restrict__ counts, int* __restrict__ blockSums, int N){
  __shared__ int red[256];
  int tid = threadIdx.x;
  int i = blockIdx.x * 256 + tid;
  red[tid] = (i < N) ? counts[i] : 0;
  __syncthreads();
  #pragma unroll
  for (int off = 128; off > 0; off >>= 1){
    if (tid < off) red[tid] += red[tid + off];
    __syncthreads();
  }
  if (tid == 0) blockSums[blockIdx.x] = red[0];
}

// scan3 with inlined block-sum scan (nb <= 256)
__global__ void k_scan3(const int* __restrict__ counts, const int* __restrict__ blockSums,
                        int* __restrict__ offsets, int* __restrict__ cursor, int N, int nb){
  __shared__ int bs[256];
  __shared__ int s[256];
  int tid = threadIdx.x;
  bs[tid] = (tid < nb) ? blockSums[tid] : 0;
  __syncthreads();
  #pragma unroll
  for (int off = 1; off < 256; off <<= 1){
    int t = (tid >= off) ? bs[tid - off] : 0;
    __syncthreads();
    bs[tid] += t;
    __syncthreads();
  }
  int myOff = (blockIdx.x == 0) ? 0 : bs[blockIdx.x - 1];
  int i = blockIdx.x * 256 + tid;
  int v = (i < N) ? counts[i] : 0;
  s[tid] = v;
  __syncthreads();
  #pragma unroll
  for (int off = 1; off < 256; off <<= 1){
    int t = (tid >= off) ? s[tid - off] : 0;
    __syncthreads();
    s[tid] += t;
    __syncthreads();
  }
  int excl = myOff + s[tid] - v;
  if (i < N){ offsets[i] = excl; cursor[i] = excl; }
  if (i == N - 1) offsets[N] = excl + v;
}

// csr record: (col, dist-bits) packed as int2
__global__ void k_fill(const int* __restrict__ row, const int* __restrict__ col,
                       const float* __restrict__ pos, int* __restrict__ cursor,
                       int2* __restrict__ csr_cd, int E){
  int e = blockIdx.x * 256 + threadIdx.x;
  if (e >= E) return;
  int r = row[e], c = col[e];
  float dx = pos[r*3+0] - pos[c*3+0];
  float dy = pos[r*3+1] - pos[c*3+1];
  float dz = pos[r*3+2] - pos[c*3+2];
  float d = sqrtf(dx*dx + dy*dy + dz*dz);
  int slot = atomicAdd(&cursor[r], 1);
  csr_cd[slot] = make_int2(c, __float_as_int(d));
}

// ---------------- merged elementwise setup ----------------
// ranges: [zero counts][init_v][prepw Wn][prepw Wo][ac][bounds]
__global__ void k_setup(const int* __restrict__ z, const float* __restrict__ emb,
                        ushortT* __restrict__ vhi, ushortT* __restrict__ vlo,
                        const float* __restrict__ Wn, ushortT* __restrict__ WnHiT,
                        ushortT* __restrict__ WnLoT,
                        const float* __restrict__ Wo, ushortT* __restrict__ WoHiT,
                        ushortT* __restrict__ WoLoT,
                        const float* __restrict__ dW, const float* __restrict__ db,
                        const float* __restrict__ We, const float* __restrict__ be,
                        float* __restrict__ a, float* __restrict__ c,
                        const int* __restrict__ batch, int* __restrict__ groupOff,
                        int* __restrict__ counts,
                        int N, int G, int B0, int B1, int B2, int B4, int B5){
  int b = blockIdx.x;
  int tid = threadIdx.x;
  if (b < B0){                               // zero counts
    int i = b * 256 + tid;
    if (i < N) counts[i] = 0;
    return;
  }
  b -= B0;
  if (b < B1){                               // init_v: split emb[z] hi/lo
    int idx = b * 256 + tid;
    if (idx < N * HDIM){
      int n = idx >> 7, f = idx & 127;
      float w = emb[z[n] * HDIM + f];
      unsigned short hi = f2bf(w);
      vhi[idx] = hi;
      vlo[idx] = f2bf(w - bf2f(hi));
    }
    return;
  }
  b -= B1;
  if (b < B2){                               // prepw Wn
    int idx = b * 256 + tid;
    if (idx < NLAYER * HDIM * HDIM){
      int mat = idx >> 14, rem = idx & 16383;
      int n = rem >> 7, k = rem & 127;
      float w = Wn[(mat << 14) + k * HDIM + n];
      unsigned short hi = f2bf(w);
      WnHiT[idx] = hi;
      WnLoT[idx] = f2bf(w - bf2f(hi));
    }
    return;
  }
  b -= B2;
  if (b < B2){                               // prepw Wo
    int idx = b * 256 + tid;
    if (idx < NLAYER * HDIM * HDIM){
      int mat = idx >> 14, rem = idx & 16383;
      int n = rem >> 7, k = rem & 127;
      float w = Wo[(mat << 14) + k * HDIM + n];
      unsigned short hi = f2bf(w);
      WoHiT[idx] = hi;
      WoLoT[idx] = f2bf(w - bf2f(hi));
    }
    return;
  }
  b -= B2;
  if (b < B4){                               // ac
    int idx = b * 256 + tid;
    if (idx < NLAYER * HDIM){
      int l = idx >> 7, f = idx & 127;
      float av = 0.f, cv = 0.f;
      for (int g = 0; g < NGAUSS; ++g){
        float we = We[(l * NGAUSS + g) * HDIM + f];
        av += dW[g] * we;
        cv += db[g] * we;
      }
      a[idx] = av;
      c[idx] = cv + be[idx];
    }
    return;
  }
  b -= B4;
  if (b < B5){                               // bounds over sorted batch
    int i = b * 256 + tid;
    if (i >= N) return;
    int bb = batch[i];
    if (i == 0){
      for (int g = 0; g <= bb; ++g) groupOff[g] = 0;
    } else {
      int pb = batch[i - 1];
      for (int g = pb + 1; g <= bb; ++g) groupOff[g] = i;
    }
    if (i == N - 1){
      for (int g = bb + 1; g <= G; ++g) groupOff[g] = N;
    }
  }
}

// 12-MFMA split-precision product: d = X(hi/lo) @ B(hi/lo)
static __device__ __forceinline__ f32x4 mfma12(const bf16x8* ahi, const bf16x8* alo,
                                               const ushortT* bph, const ushortT* bpl){
  bf16x8 bh0 = *(const bf16x8*)(bph);
  bf16x8 bh1 = *(const bf16x8*)(bph + 32);
  bf16x8 bh2 = *(const bf16x8*)(bph + 64);
  bf16x8 bh3 = *(const bf16x8*)(bph + 96);
  bf16x8 bl0 = *(const bf16x8*)(bpl);
  bf16x8 bl1 = *(const bf16x8*)(bpl + 32);
  bf16x8 bl2 = *(const bf16x8*)(bpl + 64);
  bf16x8 bl3 = *(const bf16x8*)(bpl + 96);
  f32x4 d = {0.f, 0.f, 0.f, 0.f};
  d = __builtin_amdgcn_mfma_f32_16x16x32_bf16(ahi[0], bh0, d, 0, 0, 0);
  d = __builtin_amdgcn_mfma_f32_16x16x32_bf16(ahi[1], bh1, d, 0, 0, 0);
  d = __builtin_amdgcn_mfma_f32_16x16x32_bf16(ahi[2], bh2, d, 0, 0, 0);
  d = __builtin_amdgcn_mfma_f32_16x16x32_bf16(ahi[3], bh3, d, 0, 0, 0);
  d = __builtin_amdgcn_mfma_f32_16x16x32_bf16(ahi[0], bl0, d, 0, 0, 0);
  d = __builtin_amdgcn_mfma_f32_16x16x32_bf16(ahi[1], bl1, d, 0, 0, 0);
  d = __builtin_amdgcn_mfma_f32_16x16x32_bf16(ahi[2], bl2, d, 0, 0, 0);
  d = __builtin_amdgcn_mfma_f32_16x16x32_bf16(ahi[3], bl3, d, 0, 0, 0);
  d = __builtin_amdgcn_mfma_f32_16x16x32_bf16(alo[0], bh0, d, 0, 0, 0);
  d = __builtin_amdgcn_mfma_f32_16x16x32_bf16(alo[1], bh1, d, 0, 0, 0);
  d = __builtin_amdgcn_mfma_f32_16x16x32_bf16(alo[2], bh2, d, 0, 0, 0);
  d = __builtin_amdgcn_mfma_f32_16x16x32_bf16(alo[3], bh3, d, 0, 0, 0);
  return d;
}

// per-node edge aggregation, 16-deep MLP; lane covers features f, f+1
static __device__ __forceinline__ void agg_edges(const ushortT* __restrict__ h,
    const int2* __restrict__ cd, int s, int e, int f,
    float a0, float a1, float c0, float c1, float& acc0, float& acc1){
  int j = s;
  if ((j & 1) && j < e){
    int2 q = cd[j];
    unsigned int p = *(const unsigned int*)(h + ((size_t)q.x << 7) + f);
    float dd = __int_as_float(q.y);
    acc0 = fmaf(bf2f((ushortT)p),          fmaf(dd, a0, c0), acc0);
    acc1 = fmaf(bf2f((ushortT)(p >> 16)),  fmaf(dd, a1, c1), acc1);
    ++j;
  }
  for (; j + 16 <= e; j += 16){
    int4 q[8];
    #pragma unroll
    for (int i = 0; i < 8; ++i) q[i] = *(const int4*)(cd + j + 2*i);
    unsigned int p[16];
    #pragma unroll
    for (int i = 0; i < 8; ++i){
      p[2*i]   = *(const unsigned int*)(h + ((size_t)q[i].x << 7) + f);
      p[2*i+1] = *(const unsigned int*)(h + ((size_t)q[i].z << 7) + f);
    }
    #pragma unroll
    for (int i = 0; i < 8; ++i){
      float d0 = __int_as_float(q[i].y), d1 = __int_as_float(q[i].w);
      acc0 = fmaf(bf2f((ushortT)p[2*i]),           fmaf(d0, a0, c0), acc0);
      acc1 = fmaf(bf2f((ushortT)(p[2*i]   >> 16)), fmaf(d0, a1, c1), acc1);
      acc0 = fmaf(bf2f((ushortT)p[2*i+1]),         fmaf(d1, a0, c0), acc0);
      acc1 = fmaf(bf2f((ushortT)(p[2*i+1] >> 16)), fmaf(d1, a1, c1), acc1);
    }
  }
  for (; j + 2 <= e; j += 2){
    int4 q = *(const int4*)(cd + j);
    unsigned int p0 = *(const unsigned int*)(h + ((size_t)q.x << 7) + f);
    unsigned int p1 = *(const unsigned int*)(h + ((size_t)q.z << 7) + f);
    float d0 = __int_as_float(q.y), d1 = __int_as_float(q.w);
    acc0 = fmaf(bf2f((ushortT)p0),         fmaf(d0, a0, c0), acc0);
    acc1 = fmaf(bf2f((ushortT)(p0 >> 16)), fmaf(d0, a1, c1), acc1);
    acc0 = fmaf(bf2f((ushortT)p1),         fmaf(d1, a0, c0), acc0);
    acc1 = fmaf(bf2f((ushortT)(p1 >> 16)), fmaf(d1, a1, c1), acc1);
  }
  if (j < e){
    int2 q = cd[j];
    unsigned int p = *(const unsigned int*)(h + ((size_t)q.x << 7) + f);
    float dd = __int_as_float(q.y);
    acc0 = fmaf(bf2f((ushortT)p),         fmaf(dd, a0, c0), acc0);
    acc1 = fmaf(bf2f((ushortT)(p >> 16)), fmaf(dd, a1, c1), acc1);
  }
}

// ---------------- initial GEMM: h0 = v0 @ Wn[0], bf16-hi output ----------------
__global__ __launch_bounds__(256, 4)
void k_gemm0(const ushortT* __restrict__ Xhi, const ushortT* __restrict__ Xlo,
             const ushortT* __restrict__ WhiT, const ushortT* __restrict__ WloT,
             ushortT* __restrict__ outHi, int N){
  int tid = threadIdx.x;
  int wave = tid >> 6, lane = tid & 63;
  int m = lane & 15, quad = lane >> 4;
  int ntiles = (N + 15) >> 4;
  int tile = blockIdx.x * 4 + wave;
  if (tile >= ntiles) return;
  int rowBase = tile << 4;
  int row = rowBase + m; if (row >= N) row = N - 1;

  bf16x8 ahi[4], alo[4];
  #pragma unroll
  for (int kk = 0; kk < 4; ++kk){
    ahi[kk] = *(const bf16x8*)(Xhi + ((size_t)row << 7) + kk*32 + quad*8);
    alo[kk] = *(const bf16x8*)(Xlo + ((size_t)row << 7) + kk*32 + quad*8);
  }
  #pragma unroll
  for (int ct = 0; ct < 8; ++ct){
    int ncol = ct * 16 + m;
    f32x4 d = mfma12(ahi, alo, WhiT + ((size_t)ncol << 7) + quad*8,
                               WloT + ((size_t)ncol << 7) + quad*8);
    #pragma unroll
    for (int r = 0; r < 4; ++r){
      int orow = rowBase + quad*4 + r;
      if (orow < N) outHi[((size_t)orow << 7) + ncol] = f2bf(d[r]);
    }
  }
}

// ---------------- fused layer: agg -> Wo-GEMM+ssp -> Wn-GEMM (or readout) ----
// One block = one 16-node tile. 4 waves: each aggregates 4 nodes into a shared
// LDS tile, then the 4 waves split the 8 column-tiles of each GEMM (2 each).
template<int LAST>
__global__ __launch_bounds__(256, 3)
void k_layer(const ushortT* __restrict__ h, const int* __restrict__ offsets,
             const int2* __restrict__ cd,
             const float* __restrict__ a, const float* __restrict__ c,
             const ushortT* __restrict__ WoHiT, const ushortT* __restrict__ WoLoT,
             const float* __restrict__ bo,
             const ushortT* __restrict__ WnHiT, const ushortT* __restrict__ WnLoT,
             ushortT* __restrict__ outH,
             const float* __restrict__ W1, const float* __restrict__ b1,
             const float* __restrict__ W2, const float* __restrict__ b2,
             float* __restrict__ u, int N){
  __shared__ ushortT th[16 * TSTR];
  __shared__ ushortT tl[16 * TSTR];
  __shared__ ushortT vh[LAST ? 1 : 16 * TSTR];
  __shared__ ushortT vl[LAST ? 1 : 16 * TSTR];
  __shared__ float   vf[LAST ? 16 * VSTR : 1];
  int tid = threadIdx.x;
  int wave = tid >> 6, lane = tid & 63;
  int m = lane & 15, quad = lane >> 4;
  int rowBase = blockIdx.x << 4;
  int f = lane * 2;
  float a0 = a[f], a1 = a[f+1], c0 = c[f], c1 = c[f+1];

  // phase 1: aggregate 4 nodes per wave into the shared tile
  #pragma unroll 1
  for (int i = 0; i < 4; ++i){
    int node = rowBase + wave*4 + i;
    float acc0 = 0.f, acc1 = 0.f;
    if (node < N){
      int s = offsets[node], e = offsets[node + 1];
      agg_edges(h, cd, s, e, f, a0, a1, c0, c1, acc0, acc1);
    }
    unsigned short h0 = f2bf(acc0), h1 = f2bf(acc1);
    unsigned short l0 = f2bf(acc0 - bf2f(h0)), l1 = f2bf(acc1 - bf2f(h1));
    int r = wave*4 + i;
    *(unsigned int*)(&th[r * TSTR + f]) = (unsigned int)h0 | ((unsigned int)h1 << 16);
    *(unsigned int*)(&tl[r * TSTR + f]) = (unsigned int)l0 | ((unsigned int)l1 << 16);
  }
  __syncthreads();

  // phase 2: Wo GEMM + bias + ssp; waves split the 8 column-tiles (2 each)
  bf16x8 ahi[4], alo[4];
  #pragma unroll
  for (int kk = 0; kk < 4; ++kk){
    ahi[kk] = *(const bf16x8*)(&th[m * TSTR + kk*32 + quad*8]);
    alo[kk] = *(const bf16x8*)(&tl[m * TSTR + kk*32 + quad*8]);
  }
  #pragma unroll
  for (int j = 0; j < 2; ++j){
    int ct = wave * 2 + j;
    int ncol = ct * 16 + m;
    f32x4 d = mfma12(ahi, alo, WoHiT + ((size_t)ncol << 7) + quad*8,
                               WoLoT + ((size_t)ncol << 7) + quad*8);
    float bb = bo[ncol];
    #pragma unroll
    for (int r = 0; r < 4; ++r){
      float sv = ssp(d[r] + bb);
      if (LAST){
        vf[(quad*4 + r) * VSTR + ncol] = sv;
      } else {
        unsigned short hi = f2bf(sv);
        vh[(quad*4 + r) * TSTR + ncol] = hi;
        vl[(quad*4 + r) * TSTR + ncol] = f2bf(sv - bf2f(hi));
      }
    }
  }
  __syncthreads();

  if (!LAST){
    // phase 3: h_next = v @ WnNext
    bf16x8 a2h[4], a2l[4];
    #pragma unroll
    for (int kk = 0; kk < 4; ++kk){
      a2h[kk] = *(const bf16x8*)(&vh[m * TSTR + kk*32 + quad*8]);
      a2l[kk] = *(const bf16x8*)(&vl[m * TSTR + kk*32 + quad*8]);
    }
    #pragma unroll
    for (int j = 0; j < 2; ++j){
      int ct = wave * 2 + j;
      int ncol = ct * 16 + m;
      f32x4 d = mfma12(a2h, a2l, WnHiT + ((size_t)ncol << 7) + quad*8,
                                 WnLoT + ((size_t)ncol << 7) + quad*8);
      #pragma unroll
      for (int r = 0; r < 4; ++r){
        int orow = rowBase + quad*4 + r;
        if (orow < N) outH[((size_t)orow << 7) + ncol] = f2bf(d[r]);
      }
    }
  } else {
    // phase 3: readout u[node] = ssp(v@W1+b1)@W2 + b2, 4 nodes per wave
    #pragma unroll 1
    for (int i = 0; i < 4; ++i){
      int node = rowBase + wave*4 + i;
      if (node >= N) continue;
      const float* vrow = &vf[(wave*4 + i) * VSTR];
      float t0 = b1[lane], t1 = 0.f;
      #pragma unroll 8
      for (int k = 0; k < HDIM; k += 2){
        t0 = fmaf(vrow[k],     W1[k * 64 + lane],       t0);
        t1 = fmaf(vrow[k + 1], W1[(k + 1) * 64 + lane], t1);
      }
      float partial = ssp(t0 + t1) * W2[lane];
      #pragma unroll
      for (int off = 32; off > 0; off >>= 1)
        partial += __shfl_down(partial, off, 64);
      if (lane == 0) u[node] = partial + b2[0];
    }
  }
}

// ---------------- group segment sum over sorted batch ----------------
__global__ void k_gsum(const float* __restrict__ u, const int* __restrict__ groupOff,
                       float* __restrict__ out, int G){
  int g = blockIdx.x * 4 + (threadIdx.x >> 6);
  if (g >= G) return;
  int lane = threadIdx.x & 63;
  int s = groupOff[g], e = groupOff[g + 1];
  float acc = 0.f;
  for (int j = s + lane; j < e; j += 64) acc += u[j];
  #pragma unroll
  for (int off = 32; off > 0; off >>= 1)
    acc += __shfl_down(acc, off, 64);
  if (lane == 0) out[g] = acc;
}

extern "C" void kernel_launch(void* const* d_in, const int* in_sizes, int n_in,
                              void* d_out, int out_size, void* d_ws, size_t ws_size,
                              hipStream_t stream){
  const int N = in_sizes[0];
  const int E = in_sizes[3] / 2;
  const int G = out_size;

  const int*   z     = (const int*)d_in[0];
  const float* pos   = (const float*)d_in[1];
  const int*   batch = (const int*)d_in[2];
  const int*   eidx  = (const int*)d_in[3];
  const int*   erow  = eidx;
  const int*   ecol  = eidx + E;
  const float* emb   = (const float*)d_in[4];
  const float* dW    = (const float*)d_in[5];
  const float* db    = (const float*)d_in[6];
  const float* Wn    = (const float*)d_in[7];
  const float* We    = (const float*)d_in[8];
  const float* be    = (const float*)d_in[9];
  const float* Wo    = (const float*)d_in[10];
  const float* bo    = (const float*)d_in[11];
  const float* W1    = (const float*)d_in[12];
  const float* b1    = (const float*)d_in[13];
  const float* W2    = (const float*)d_in[14];
  const float* b2    = (const float*)d_in[15];

  char* ws = (char*)d_ws;
  size_t off = 0;
  auto alloc = [&](size_t bytes) -> char* {
    char* p = ws + off;
    off = (off + bytes + 255) & ~(size_t)255;
    return p;
  };
  int nscanb = (N + 255) / 256;
  int*     counts   = (int*)    alloc((size_t)N * 4);
  int*     offsets  = (int*)    alloc((size_t)(N + 1) * 4);
  int*     cursor   = (int*)    alloc((size_t)N * 4);
  int*     blockSums= (int*)    alloc((size_t)nscanb * 4);
  int2*    csr_cd   = (int2*)   alloc((size_t)E * 8);
  ushortT* h0       = (ushortT*)alloc((size_t)N * HDIM * 2);
  ushortT* h1       = (ushortT*)alloc((size_t)N * HDIM * 2);
  ushortT* vhi      = (ushortT*)alloc((size_t)N * HDIM * 2);
  ushortT* vlo      = (ushortT*)alloc((size_t)N * HDIM * 2);
  ushortT* WnHiT    = (ushortT*)alloc((size_t)NLAYER * HDIM * HDIM * 2);
  ushortT* WnLoT    = (ushortT*)alloc((size_t)NLAYER * HDIM * HDIM * 2);
  ushortT* WoHiT    = (ushortT*)alloc((size_t)NLAYER * HDIM * HDIM * 2);
  ushortT* WoLoT    = (ushortT*)alloc((size_t)NLAYER * HDIM * HDIM * 2);
  float*   a        = (float*)  alloc((size_t)NLAYER * HDIM * 4);
  float*   c        = (float*)  alloc((size_t)NLAYER * HDIM * 4);
  float*   u        = (float*)  alloc((size_t)N * 4);
  int*     groupOff = (int*)    alloc((size_t)(G + 1) * 4);

  // merged setup: zero counts + init_v + prepw(Wn) + prepw(Wo) + ac + bounds
  int B0 = (N + 255) / 256;
  int B1 = (N * HDIM + 255) / 256;
  int B2 = (NLAYER * HDIM * HDIM + 255) / 256;
  int B4 = (NLAYER * HDIM + 255) / 256;
  int B5 = (N + 255) / 256;
  k_setup<<<B0 + B1 + 2*B2 + B4 + B5, 256, 0, stream>>>(
      z, emb, vhi, vlo, Wn, WnHiT, WnLoT, Wo, WoHiT, WoLoT,
      dW, db, We, be, a, c, batch, groupOff, counts, N, G, B0, B1, B2, B4, B5);

  k_count<<<(E + 255) / 256, 256, 0, stream>>>(erow, counts, E);
  k_scan1<<<nscanb, 256, 0, stream>>>(counts, blockSums, N);
  k_scan3<<<nscanb, 256, 0, stream>>>(counts, blockSums, offsets, cursor, N, nscanb);
  k_fill<<<(E + 255) / 256, 256, 0, stream>>>(erow, ecol, pos, cursor, csr_cd, E);

  int ntiles = (N + 15) >> 4;
  k_gemm0<<<(ntiles + 3) / 4, 256, 0, stream>>>(vhi, vlo, WnHiT, WnLoT, h0, N);

  for (int l = 0; l < NLAYER; ++l){
    size_t wo = (size_t)l * HDIM * HDIM;
    const ushortT* hin = (l & 1) ? h1 : h0;
    ushortT*       hout = (l & 1) ? h0 : h1;
    if (l < NLAYER - 1){
      size_t wn = (size_t)(l + 1) * HDIM * HDIM;
      k_layer<0><<<ntiles, 256, 0, stream>>>(hin, offsets, csr_cd,
          a + l * HDIM, c + l * HDIM, WoHiT + wo, WoLoT + wo, bo + (size_t)l * HDIM,
          WnHiT + wn, WnLoT + wn, hout,
          nullptr, nullptr, nullptr, nullptr, nullptr, N);
    } else {
      k_layer<1><<<ntiles, 256, 0, stream>>>(hin, offsets, csr_cd,
          a + l * HDIM, c + l * HDIM, WoHiT + wo, WoLoT + wo, bo + (size_t)l * HDIM,
          nullptr, nullptr, nullptr,
          W1, b1, W2, b2, u, N);
    }
  }
  k_gsum<<<(G + 3) / 4, 256, 0, stream>>>(u, groupOff, (float*)d_out, G);
}

// Round 9
// 1081.469 us; speedup vs baseline: 1.0458x; 1.0458x over previous
//
#include <hip/hip_runtime.h>
#include <math.h>

#define HDIM 128
#define NGAUSS 50
#define NLAYER 6
#define TSTR 136   // LDS bf16 tile row stride (shorts); %8==0 keeps ds_read_b128 aligned
#define VSTR 132   // LDS f32 tile row stride (floats)

typedef unsigned short ushortT;
typedef __attribute__((ext_vector_type(8))) short bf16x8;
typedef __attribute__((ext_vector_type(4))) float f32x4;

static __device__ __forceinline__ float bf2f(unsigned short u){
  union { unsigned int i; float f; } x; x.i = ((unsigned int)u) << 16; return x.f;
}
static __device__ __forceinline__ unsigned short f2bf(float f){
  union { float f; unsigned int i; } x; x.f = f;
  unsigned int i = x.i;
  unsigned int r = (i + 0x7FFFu + ((i >> 16) & 1u)) >> 16;
  return (unsigned short)r;
}
// softplus(x) - log(2), numerically stable
static __device__ __forceinline__ float ssp(float x){
  float sp = fmaxf(x, 0.0f) + log1pf(expf(-fabsf(x)));
  return sp - 0.69314718055994530942f;
}

// ---------------- CSR build ----------------
__global__ void k_count(const int* __restrict__ row, int* __restrict__ counts, int E){
  int e = blockIdx.x * 256 + threadIdx.x;
  if (e < E) atomicAdd(&counts[row[e]], 1);
}

__global__ void k_scan1(const int* __restrict__ counts, int* __restrict__ blockSums, int N){
  __shared__ int red[256];
  int tid = threadIdx.x;
  int i = blockIdx.x * 256 + tid;
  red[tid] = (i < N) ? counts[i] : 0;
  __syncthreads();
  #pragma unroll
  for (int off = 128; off > 0; off >>= 1){
    if (tid < off) red[tid] += red[tid + off];
    __syncthreads();
  }
  if (tid == 0) blockSums[blockIdx.x] = red[0];
}

// scan3 with inlined block-sum scan (nb <= 256)
__global__ void k_scan3(const int* __restrict__ counts, const int* __restrict__ blockSums,
                        int* __restrict__ offsets, int* __restrict__ cursor, int N, int nb){
  __shared__ int bs[256];
  __shared__ int s[256];
  int tid = threadIdx.x;
  bs[tid] = (tid < nb) ? blockSums[tid] : 0;
  __syncthreads();
  #pragma unroll
  for (int off = 1; off < 256; off <<= 1){
    int t = (tid >= off) ? bs[tid - off] : 0;
    __syncthreads();
    bs[tid] += t;
    __syncthreads();
  }
  int myOff = (blockIdx.x == 0) ? 0 : bs[blockIdx.x - 1];
  int i = blockIdx.x * 256 + tid;
  int v = (i < N) ? counts[i] : 0;
  s[tid] = v;
  __syncthreads();
  #pragma unroll
  for (int off = 1; off < 256; off <<= 1){
    int t = (tid >= off) ? s[tid - off] : 0;
    __syncthreads();
    s[tid] += t;
    __syncthreads();
  }
  int excl = myOff + s[tid] - v;
  if (i < N){ offsets[i] = excl; cursor[i] = excl; }
  if (i == N - 1) offsets[N] = excl + v;
}

// csr record: (col, dist-bits) packed as int2
__global__ void k_fill(const int* __restrict__ row, const int* __restrict__ col,
                       const float* __restrict__ pos, int* __restrict__ cursor,
                       int2* __restrict__ csr_cd, int E){
  int e = blockIdx.x * 256 + threadIdx.x;
  if (e >= E) return;
  int r = row[e], c = col[e];
  float dx = pos[r*3+0] - pos[c*3+0];
  float dy = pos[r*3+1] - pos[c*3+1];
  float dz = pos[r*3+2] - pos[c*3+2];
  float d = sqrtf(dx*dx + dy*dy + dz*dz);
  int slot = atomicAdd(&cursor[r], 1);
  csr_cd[slot] = make_int2(c, __float_as_int(d));
}

// ---------------- merged elementwise setup ----------------
// ranges: [zero counts][init_v][prepw Wn][prepw Wo][ac][bounds]
__global__ void k_setup(const int* __restrict__ z, const float* __restrict__ emb,
                        ushortT* __restrict__ vhi, ushortT* __restrict__ vlo,
                        const float* __restrict__ Wn, ushortT* __restrict__ WnHiT,
                        ushortT* __restrict__ WnLoT,
                        const float* __restrict__ Wo, ushortT* __restrict__ WoHiT,
                        ushortT* __restrict__ WoLoT,
                        const float* __restrict__ dW, const float* __restrict__ db,
                        const float* __restrict__ We, const float* __restrict__ be,
                        float* __restrict__ a, float* __restrict__ c,
                        const int* __restrict__ batch, int* __restrict__ groupOff,
                        int* __restrict__ counts,
                        int N, int G, int B0, int B1, int B2, int B4, int B5){
  int b = blockIdx.x;
  int tid = threadIdx.x;
  if (b < B0){                               // zero counts
    int i = b * 256 + tid;
    if (i < N) counts[i] = 0;
    return;
  }
  b -= B0;
  if (b < B1){                               // init_v: split emb[z] hi/lo
    int idx = b * 256 + tid;
    if (idx < N * HDIM){
      int n = idx >> 7, f = idx & 127;
      float w = emb[z[n] * HDIM + f];
      unsigned short hi = f2bf(w);
      vhi[idx] = hi;
      vlo[idx] = f2bf(w - bf2f(hi));
    }
    return;
  }
  b -= B1;
  if (b < B2){                               // prepw Wn
    int idx = b * 256 + tid;
    if (idx < NLAYER * HDIM * HDIM){
      int mat = idx >> 14, rem = idx & 16383;
      int n = rem >> 7, k = rem & 127;
      float w = Wn[(mat << 14) + k * HDIM + n];
      unsigned short hi = f2bf(w);
      WnHiT[idx] = hi;
      WnLoT[idx] = f2bf(w - bf2f(hi));
    }
    return;
  }
  b -= B2;
  if (b < B2){                               // prepw Wo
    int idx = b * 256 + tid;
    if (idx < NLAYER * HDIM * HDIM){
      int mat = idx >> 14, rem = idx & 16383;
      int n = rem >> 7, k = rem & 127;
      float w = Wo[(mat << 14) + k * HDIM + n];
      unsigned short hi = f2bf(w);
      WoHiT[idx] = hi;
      WoLoT[idx] = f2bf(w - bf2f(hi));
    }
    return;
  }
  b -= B2;
  if (b < B4){                               // ac
    int idx = b * 256 + tid;
    if (idx < NLAYER * HDIM){
      int l = idx >> 7, f = idx & 127;
      float av = 0.f, cv = 0.f;
      for (int g = 0; g < NGAUSS; ++g){
        float we = We[(l * NGAUSS + g) * HDIM + f];
        av += dW[g] * we;
        cv += db[g] * we;
      }
      a[idx] = av;
      c[idx] = cv + be[idx];
    }
    return;
  }
  b -= B4;
  if (b < B5){                               // bounds over sorted batch
    int i = b * 256 + tid;
    if (i >= N) return;
    int bb = batch[i];
    if (i == 0){
      for (int g = 0; g <= bb; ++g) groupOff[g] = 0;
    } else {
      int pb = batch[i - 1];
      for (int g = pb + 1; g <= bb; ++g) groupOff[g] = i;
    }
    if (i == N - 1){
      for (int g = bb + 1; g <= G; ++g) groupOff[g] = N;
    }
  }
}

// 12-MFMA split-precision product: d = X(hi/lo) @ B(hi/lo)
static __device__ __forceinline__ f32x4 mfma12(const bf16x8* ahi, const bf16x8* alo,
                                               const ushortT* bph, const ushortT* bpl){
  bf16x8 bh0 = *(const bf16x8*)(bph);
  bf16x8 bh1 = *(const bf16x8*)(bph + 32);
  bf16x8 bh2 = *(const bf16x8*)(bph + 64);
  bf16x8 bh3 = *(const bf16x8*)(bph + 96);
  bf16x8 bl0 = *(const bf16x8*)(bpl);
  bf16x8 bl1 = *(const bf16x8*)(bpl + 32);
  bf16x8 bl2 = *(const bf16x8*)(bpl + 64);
  bf16x8 bl3 = *(const bf16x8*)(bpl + 96);
  f32x4 d = {0.f, 0.f, 0.f, 0.f};
  d = __builtin_amdgcn_mfma_f32_16x16x32_bf16(ahi[0], bh0, d, 0, 0, 0);
  d = __builtin_amdgcn_mfma_f32_16x16x32_bf16(ahi[1], bh1, d, 0, 0, 0);
  d = __builtin_amdgcn_mfma_f32_16x16x32_bf16(ahi[2], bh2, d, 0, 0, 0);
  d = __builtin_amdgcn_mfma_f32_16x16x32_bf16(ahi[3], bh3, d, 0, 0, 0);
  d = __builtin_amdgcn_mfma_f32_16x16x32_bf16(ahi[0], bl0, d, 0, 0, 0);
  d = __builtin_amdgcn_mfma_f32_16x16x32_bf16(ahi[1], bl1, d, 0, 0, 0);
  d = __builtin_amdgcn_mfma_f32_16x16x32_bf16(ahi[2], bl2, d, 0, 0, 0);
  d = __builtin_amdgcn_mfma_f32_16x16x32_bf16(ahi[3], bl3, d, 0, 0, 0);
  d = __builtin_amdgcn_mfma_f32_16x16x32_bf16(alo[0], bh0, d, 0, 0, 0);
  d = __builtin_amdgcn_mfma_f32_16x16x32_bf16(alo[1], bh1, d, 0, 0, 0);
  d = __builtin_amdgcn_mfma_f32_16x16x32_bf16(alo[2], bh2, d, 0, 0, 0);
  d = __builtin_amdgcn_mfma_f32_16x16x32_bf16(alo[3], bh3, d, 0, 0, 0);
  return d;
}

// per-node edge aggregation, 16-deep MLP; lane covers features f, f+1
static __device__ __forceinline__ void agg_edges(const ushortT* __restrict__ h,
    const int2* __restrict__ cd, int s, int e, int f,
    float a0, float a1, float c0, float c1, float& acc0, float& acc1){
  int j = s;
  if ((j & 1) && j < e){
    int2 q = cd[j];
    unsigned int p = *(const unsigned int*)(h + ((size_t)q.x << 7) + f);
    float dd = __int_as_float(q.y);
    acc0 = fmaf(bf2f((ushortT)p),          fmaf(dd, a0, c0), acc0);
    acc1 = fmaf(bf2f((ushortT)(p >> 16)),  fmaf(dd, a1, c1), acc1);
    ++j;
  }
  for (; j + 16 <= e; j += 16){
    int4 q[8];
    #pragma unroll
    for (int i = 0; i < 8; ++i) q[i] = *(const int4*)(cd + j + 2*i);
    unsigned int p[16];
    #pragma unroll
    for (int i = 0; i < 8; ++i){
      p[2*i]   = *(const unsigned int*)(h + ((size_t)q[i].x << 7) + f);
      p[2*i+1] = *(const unsigned int*)(h + ((size_t)q[i].z << 7) + f);
    }
    #pragma unroll
    for (int i = 0; i < 8; ++i){
      float d0 = __int_as_float(q[i].y), d1 = __int_as_float(q[i].w);
      acc0 = fmaf(bf2f((ushortT)p[2*i]),           fmaf(d0, a0, c0), acc0);
      acc1 = fmaf(bf2f((ushortT)(p[2*i]   >> 16)), fmaf(d0, a1, c1), acc1);
      acc0 = fmaf(bf2f((ushortT)p[2*i+1]),         fmaf(d1, a0, c0), acc0);
      acc1 = fmaf(bf2f((ushortT)(p[2*i+1] >> 16)), fmaf(d1, a1, c1), acc1);
    }
  }
  for (; j + 2 <= e; j += 2){
    int4 q = *(const int4*)(cd + j);
    unsigned int p0 = *(const unsigned int*)(h + ((size_t)q.x << 7) + f);
    unsigned int p1 = *(const unsigned int*)(h + ((size_t)q.z << 7) + f);
    float d0 = __int_as_float(q.y), d1 = __int_as_float(q.w);
    acc0 = fmaf(bf2f((ushortT)p0),         fmaf(d0, a0, c0), acc0);
    acc1 = fmaf(bf2f((ushortT)(p0 >> 16)), fmaf(d0, a1, c1), acc1);
    acc0 = fmaf(bf2f((ushortT)p1),         fmaf(d1, a0, c0), acc0);
    acc1 = fmaf(bf2f((ushortT)(p1 >> 16)), fmaf(d1, a1, c1), acc1);
  }
  if (j < e){
    int2 q = cd[j];
    unsigned int p = *(const unsigned int*)(h + ((size_t)q.x << 7) + f);
    float dd = __int_as_float(q.y);
    acc0 = fmaf(bf2f((ushortT)p),         fmaf(dd, a0, c0), acc0);
    acc1 = fmaf(bf2f((ushortT)(p >> 16)), fmaf(dd, a1, c1), acc1);
  }
}

// ---------------- initial GEMM: h0 = v0 @ Wn[0], bf16-hi output ----------------
__global__ __launch_bounds__(256, 4)
void k_gemm0(const ushortT* __restrict__ Xhi, const ushortT* __restrict__ Xlo,
             const ushortT* __restrict__ WhiT, const ushortT* __restrict__ WloT,
             ushortT* __restrict__ outHi, int N){
  int tid = threadIdx.x;
  int wave = tid >> 6, lane = tid & 63;
  int m = lane & 15, quad = lane >> 4;
  int ntiles = (N + 15) >> 4;
  int tile = blockIdx.x * 4 + wave;
  if (tile >= ntiles) return;
  int rowBase = tile << 4;
  int row = rowBase + m; if (row >= N) row = N - 1;

  bf16x8 ahi[4], alo[4];
  #pragma unroll
  for (int kk = 0; kk < 4; ++kk){
    ahi[kk] = *(const bf16x8*)(Xhi + ((size_t)row << 7) + kk*32 + quad*8);
    alo[kk] = *(const bf16x8*)(Xlo + ((size_t)row << 7) + kk*32 + quad*8);
  }
  #pragma unroll
  for (int ct = 0; ct < 8; ++ct){
    int ncol = ct * 16 + m;
    f32x4 d = mfma12(ahi, alo, WhiT + ((size_t)ncol << 7) + quad*8,
                               WloT + ((size_t)ncol << 7) + quad*8);
    #pragma unroll
    for (int r = 0; r < 4; ++r){
      int orow = rowBase + quad*4 + r;
      if (orow < N) outHi[((size_t)orow << 7) + ncol] = f2bf(d[r]);
    }
  }
}

// ---------------- fused layer: agg -> Wo-GEMM+ssp -> Wn-GEMM (or readout) ----
// One block = one 16-node tile, 1024 threads = 16 waves.
// Phase 1: wave w aggregates node rowBase+w (max gather parallelism: 50k waves).
// Phase 2: waves 0-7 do the 8 column-tiles of the Wo GEMM.
// Phase 3: waves 8-15 do the Wn GEMM (or all 16 waves do readout).
template<int LAST>
__global__ __launch_bounds__(1024, 8)
void k_layer(const ushortT* __restrict__ h, const int* __restrict__ offsets,
             const int2* __restrict__ cd,
             const float* __restrict__ a, const float* __restrict__ c,
             const ushortT* __restrict__ WoHiT, const ushortT* __restrict__ WoLoT,
             const float* __restrict__ bo,
             const ushortT* __restrict__ WnHiT, const ushortT* __restrict__ WnLoT,
             ushortT* __restrict__ outH,
             const float* __restrict__ W1, const float* __restrict__ b1,
             const float* __restrict__ W2, const float* __restrict__ b2,
             float* __restrict__ u, int N){
  __shared__ ushortT th[16 * TSTR];
  __shared__ ushortT tl[16 * TSTR];
  __shared__ ushortT vh[LAST ? 1 : 16 * TSTR];
  __shared__ ushortT vl[LAST ? 1 : 16 * TSTR];
  __shared__ float   vf[LAST ? 16 * VSTR : 1];
  int tid = threadIdx.x;
  int wave = tid >> 6, lane = tid & 63;
  int m = lane & 15, quad = lane >> 4;
  int rowBase = blockIdx.x << 4;
  int f = lane * 2;

  // phase 1: each wave aggregates one node into the shared tile
  {
    float a0 = a[f], a1 = a[f+1], c0 = c[f], c1 = c[f+1];
    int node = rowBase + wave;
    float acc0 = 0.f, acc1 = 0.f;
    if (node < N){
      int s = offsets[node], e = offsets[node + 1];
      agg_edges(h, cd, s, e, f, a0, a1, c0, c1, acc0, acc1);
    }
    unsigned short h0 = f2bf(acc0), h1 = f2bf(acc1);
    unsigned short l0 = f2bf(acc0 - bf2f(h0)), l1 = f2bf(acc1 - bf2f(h1));
    *(unsigned int*)(&th[wave * TSTR + f]) = (unsigned int)h0 | ((unsigned int)h1 << 16);
    *(unsigned int*)(&tl[wave * TSTR + f]) = (unsigned int)l0 | ((unsigned int)l1 << 16);
  }
  __syncthreads();

  // phase 2: Wo GEMM + bias + ssp; waves 0-7 take one column-tile each
  if (wave < 8){
    bf16x8 ahi[4], alo[4];
    #pragma unroll
    for (int kk = 0; kk < 4; ++kk){
      ahi[kk] = *(const bf16x8*)(&th[m * TSTR + kk*32 + quad*8]);
      alo[kk] = *(const bf16x8*)(&tl[m * TSTR + kk*32 + quad*8]);
    }
    int ncol = wave * 16 + m;
    f32x4 d = mfma12(ahi, alo, WoHiT + ((size_t)ncol << 7) + quad*8,
                               WoLoT + ((size_t)ncol << 7) + quad*8);
    float bb = bo[ncol];
    #pragma unroll
    for (int r = 0; r < 4; ++r){
      float sv = ssp(d[r] + bb);
      if (LAST){
        vf[(quad*4 + r) * VSTR + ncol] = sv;
      } else {
        unsigned short hi = f2bf(sv);
        vh[(quad*4 + r) * TSTR + ncol] = hi;
        vl[(quad*4 + r) * TSTR + ncol] = f2bf(sv - bf2f(hi));
      }
    }
  }
  __syncthreads();

  if (!LAST){
    // phase 3: h_next = v @ WnNext; waves 8-15 take one column-tile each
    if (wave >= 8){
      bf16x8 a2h[4], a2l[4];
      #pragma unroll
      for (int kk = 0; kk < 4; ++kk){
        a2h[kk] = *(const bf16x8*)(&vh[m * TSTR + kk*32 + quad*8]);
        a2l[kk] = *(const bf16x8*)(&vl[m * TSTR + kk*32 + quad*8]);
      }
      int ncol = (wave - 8) * 16 + m;
      f32x4 d = mfma12(a2h, a2l, WnHiT + ((size_t)ncol << 7) + quad*8,
                                 WnLoT + ((size_t)ncol << 7) + quad*8);
      #pragma unroll
      for (int r = 0; r < 4; ++r){
        int orow = rowBase + quad*4 + r;
        if (orow < N) outH[((size_t)orow << 7) + ncol] = f2bf(d[r]);
      }
    }
  } else {
    // phase 3: readout u[node] = ssp(v@W1+b1)@W2 + b2, one node per wave
    int node = rowBase + wave;
    if (node < N){
      const float* vrow = &vf[wave * VSTR];
      float t0 = b1[lane], t1 = 0.f;
      #pragma unroll 8
      for (int k = 0; k < HDIM; k += 2){
        t0 = fmaf(vrow[k],     W1[k * 64 + lane],       t0);
        t1 = fmaf(vrow[k + 1], W1[(k + 1) * 64 + lane], t1);
      }
      float partial = ssp(t0 + t1) * W2[lane];
      #pragma unroll
      for (int off = 32; off > 0; off >>= 1)
        partial += __shfl_down(partial, off, 64);
      if (lane == 0) u[node] = partial + b2[0];
    }
  }
}

// ---------------- group segment sum over sorted batch ----------------
__global__ void k_gsum(const float* __restrict__ u, const int* __restrict__ groupOff,
                       float* __restrict__ out, int G){
  int g = blockIdx.x * 4 + (threadIdx.x >> 6);
  if (g >= G) return;
  int lane = threadIdx.x & 63;
  int s = groupOff[g], e = groupOff[g + 1];
  float acc = 0.f;
  for (int j = s + lane; j < e; j += 64) acc += u[j];
  #pragma unroll
  for (int off = 32; off > 0; off >>= 1)
    acc += __shfl_down(acc, off, 64);
  if (lane == 0) out[g] = acc;
}

extern "C" void kernel_launch(void* const* d_in, const int* in_sizes, int n_in,
                              void* d_out, int out_size, void* d_ws, size_t ws_size,
                              hipStream_t stream){
  const int N = in_sizes[0];
  const int E = in_sizes[3] / 2;
  const int G = out_size;

  const int*   z     = (const int*)d_in[0];
  const float* pos   = (const float*)d_in[1];
  const int*   batch = (const int*)d_in[2];
  const int*   eidx  = (const int*)d_in[3];
  const int*   erow  = eidx;
  const int*   ecol  = eidx + E;
  const float* emb   = (const float*)d_in[4];
  const float* dW    = (const float*)d_in[5];
  const float* db    = (const float*)d_in[6];
  const float* Wn    = (const float*)d_in[7];
  const float* We    = (const float*)d_in[8];
  const float* be    = (const float*)d_in[9];
  const float* Wo    = (const float*)d_in[10];
  const float* bo    = (const float*)d_in[11];
  const float* W1    = (const float*)d_in[12];
  const float* b1    = (const float*)d_in[13];
  const float* W2    = (const float*)d_in[14];
  const float* b2    = (const float*)d_in[15];

  char* ws = (char*)d_ws;
  size_t off = 0;
  auto alloc = [&](size_t bytes) -> char* {
    char* p = ws + off;
    off = (off + bytes + 255) & ~(size_t)255;
    return p;
  };
  int nscanb = (N + 255) / 256;
  int*     counts   = (int*)    alloc((size_t)N * 4);
  int*     offsets  = (int*)    alloc((size_t)(N + 1) * 4);
  int*     cursor   = (int*)    alloc((size_t)N * 4);
  int*     blockSums= (int*)    alloc((size_t)nscanb * 4);
  int2*    csr_cd   = (int2*)   alloc((size_t)E * 8);
  ushortT* h0       = (ushortT*)alloc((size_t)N * HDIM * 2);
  ushortT* h1       = (ushortT*)alloc((size_t)N * HDIM * 2);
  ushortT* vhi      = (ushortT*)alloc((size_t)N * HDIM * 2);
  ushortT* vlo      = (ushortT*)alloc((size_t)N * HDIM * 2);
  ushortT* WnHiT    = (ushortT*)alloc((size_t)NLAYER * HDIM * HDIM * 2);
  ushortT* WnLoT    = (ushortT*)alloc((size_t)NLAYER * HDIM * HDIM * 2);
  ushortT* WoHiT    = (ushortT*)alloc((size_t)NLAYER * HDIM * HDIM * 2);
  ushortT* WoLoT    = (ushortT*)alloc((size_t)NLAYER * HDIM * HDIM * 2);
  float*   a        = (float*)  alloc((size_t)NLAYER * HDIM * 4);
  float*   c        = (float*)  alloc((size_t)NLAYER * HDIM * 4);
  float*   u        = (float*)  alloc((size_t)N * 4);
  int*     groupOff = (int*)    alloc((size_t)(G + 1) * 4);

  // merged setup: zero counts + init_v + prepw(Wn) + prepw(Wo) + ac + bounds
  int B0 = (N + 255) / 256;
  int B1 = (N * HDIM + 255) / 256;
  int B2 = (NLAYER * HDIM * HDIM + 255) / 256;
  int B4 = (NLAYER * HDIM + 255) / 256;
  int B5 = (N + 255) / 256;
  k_setup<<<B0 + B1 + 2*B2 + B4 + B5, 256, 0, stream>>>(
      z, emb, vhi, vlo, Wn, WnHiT, WnLoT, Wo, WoHiT, WoLoT,
      dW, db, We, be, a, c, batch, groupOff, counts, N, G, B0, B1, B2, B4, B5);

  k_count<<<(E + 255) / 256, 256, 0, stream>>>(erow, counts, E);
  k_scan1<<<nscanb, 256, 0, stream>>>(counts, blockSums, N);
  k_scan3<<<nscanb, 256, 0, stream>>>(counts, blockSums, offsets, cursor, N, nscanb);
  k_fill<<<(E + 255) / 256, 256, 0, stream>>>(erow, ecol, pos, cursor, csr_cd, E);

  int ntiles = (N + 15) >> 4;
  k_gemm0<<<(ntiles + 3) / 4, 256, 0, stream>>>(vhi, vlo, WnHiT, WnLoT, h0, N);

  for (int l = 0; l < NLAYER; ++l){
    size_t wo = (size_t)l * HDIM * HDIM;
    const ushortT* hin = (l & 1) ? h1 : h0;
    ushortT*       hout = (l & 1) ? h0 : h1;
    if (l < NLAYER - 1){
      size_t wn = (size_t)(l + 1) * HDIM * HDIM;
      k_layer<0><<<ntiles, 1024, 0, stream>>>(hin, offsets, csr_cd,
          a + l * HDIM, c + l * HDIM, WoHiT + wo, WoLoT + wo, bo + (size_t)l * HDIM,
          WnHiT + wn, WnLoT + wn, hout,
          nullptr, nullptr, nullptr, nullptr, nullptr, N);
    } else {
      k_layer<1><<<ntiles, 1024, 0, stream>>>(hin, offsets, csr_cd,
          a + l * HDIM, c + l * HDIM, WoHiT + wo, WoLoT + wo, bo + (size_t)l * HDIM,
          nullptr, nullptr, nullptr,
          W1, b1, W2, b2, u, N);
    }
  }
  k_gsum<<<(G + 3) / 4, 256, 0, stream>>>(u, groupOff, (float*)d_out, G);
}

// Round 10
// 1057.255 us; speedup vs baseline: 1.0697x; 1.0229x over previous
//
#include <hip/hip_runtime.h>
#include <math.h>

#define HDIM 128
#define NGAUSS 50
#define NLAYER 6
#define TSTR 136   // LDS bf16 tile row stride (shorts); %8==0 keeps ds_read_b128 aligned
#define VSTR 132   // LDS f32 tile row stride (floats)

typedef unsigned short ushortT;
typedef __attribute__((ext_vector_type(8))) short bf16x8;
typedef __attribute__((ext_vector_type(4))) float f32x4;

static __device__ __forceinline__ float bf2f(unsigned short u){
  union { unsigned int i; float f; } x; x.i = ((unsigned int)u) << 16; return x.f;
}
static __device__ __forceinline__ unsigned short f2bf(float f){
  union { float f; unsigned int i; } x; x.f = f;
  unsigned int i = x.i;
  unsigned int r = (i + 0x7FFFu + ((i >> 16) & 1u)) >> 16;
  return (unsigned short)r;
}
// softplus(x) - log(2), numerically stable
static __device__ __forceinline__ float ssp(float x){
  float sp = fmaxf(x, 0.0f) + log1pf(expf(-fabsf(x)));
  return sp - 0.69314718055994530942f;
}

// ---------------- CSR build ----------------
__global__ void k_count(const int* __restrict__ row, int* __restrict__ counts, int E){
  int e = blockIdx.x * 256 + threadIdx.x;
  if (e < E) atomicAdd(&counts[row[e]], 1);
}

__global__ void k_scan1(const int* __restrict__ counts, int* __restrict__ blockSums, int N){
  __shared__ int red[256];
  int tid = threadIdx.x;
  int i = blockIdx.x * 256 + tid;
  red[tid] = (i < N) ? counts[i] : 0;
  __syncthreads();
  #pragma unroll
  for (int off = 128; off > 0; off >>= 1){
    if (tid < off) red[tid] += red[tid + off];
    __syncthreads();
  }
  if (tid == 0) blockSums[blockIdx.x] = red[0];
}

// scan3 with inlined block-sum scan (nb <= 256)
__global__ void k_scan3(const int* __restrict__ counts, const int* __restrict__ blockSums,
                        int* __restrict__ offsets, int* __restrict__ cursor, int N, int nb){
  __shared__ int bs[256];
  __shared__ int s[256];
  int tid = threadIdx.x;
  bs[tid] = (tid < nb) ? blockSums[tid] : 0;
  __syncthreads();
  #pragma unroll
  for (int off = 1; off < 256; off <<= 1){
    int t = (tid >= off) ? bs[tid - off] : 0;
    __syncthreads();
    bs[tid] += t;
    __syncthreads();
  }
  int myOff = (blockIdx.x == 0) ? 0 : bs[blockIdx.x - 1];
  int i = blockIdx.x * 256 + tid;
  int v = (i < N) ? counts[i] : 0;
  s[tid] = v;
  __syncthreads();
  #pragma unroll
  for (int off = 1; off < 256; off <<= 1){
    int t = (tid >= off) ? s[tid - off] : 0;
    __syncthreads();
    s[tid] += t;
    __syncthreads();
  }
  int excl = myOff + s[tid] - v;
  if (i < N){ offsets[i] = excl; cursor[i] = excl; }
  if (i == N - 1) offsets[N] = excl + v;
}

// csr record: (col, dist-bits) packed as int2
__global__ void k_fill(const int* __restrict__ row, const int* __restrict__ col,
                       const float* __restrict__ pos, int* __restrict__ cursor,
                       int2* __restrict__ csr_cd, int E){
  int e = blockIdx.x * 256 + threadIdx.x;
  if (e >= E) return;
  int r = row[e], c = col[e];
  float dx = pos[r*3+0] - pos[c*3+0];
  float dy = pos[r*3+1] - pos[c*3+1];
  float dz = pos[r*3+2] - pos[c*3+2];
  float d = sqrtf(dx*dx + dy*dy + dz*dz);
  int slot = atomicAdd(&cursor[r], 1);
  csr_cd[slot] = make_int2(c, __float_as_int(d));
}

// ---------------- merged elementwise setup ----------------
// ranges: [zero counts][init_v][prepw Wn][prepw Wo][ac][bounds]
__global__ void k_setup(const int* __restrict__ z, const float* __restrict__ emb,
                        ushortT* __restrict__ vhi, ushortT* __restrict__ vlo,
                        const float* __restrict__ Wn, ushortT* __restrict__ WnHiT,
                        ushortT* __restrict__ WnLoT,
                        const float* __restrict__ Wo, ushortT* __restrict__ WoHiT,
                        ushortT* __restrict__ WoLoT,
                        const float* __restrict__ dW, const float* __restrict__ db,
                        const float* __restrict__ We, const float* __restrict__ be,
                        float* __restrict__ a, float* __restrict__ c,
                        const int* __restrict__ batch, int* __restrict__ groupOff,
                        int* __restrict__ counts,
                        int N, int G, int B0, int B1, int B2, int B4, int B5){
  int b = blockIdx.x;
  int tid = threadIdx.x;
  if (b < B0){                               // zero counts
    int i = b * 256 + tid;
    if (i < N) counts[i] = 0;
    return;
  }
  b -= B0;
  if (b < B1){                               // init_v: split emb[z] hi/lo
    int idx = b * 256 + tid;
    if (idx < N * HDIM){
      int n = idx >> 7, f = idx & 127;
      float w = emb[z[n] * HDIM + f];
      unsigned short hi = f2bf(w);
      vhi[idx] = hi;
      vlo[idx] = f2bf(w - bf2f(hi));
    }
    return;
  }
  b -= B1;
  if (b < B2){                               // prepw Wn
    int idx = b * 256 + tid;
    if (idx < NLAYER * HDIM * HDIM){
      int mat = idx >> 14, rem = idx & 16383;
      int n = rem >> 7, k = rem & 127;
      float w = Wn[(mat << 14) + k * HDIM + n];
      unsigned short hi = f2bf(w);
      WnHiT[idx] = hi;
      WnLoT[idx] = f2bf(w - bf2f(hi));
    }
    return;
  }
  b -= B2;
  if (b < B2){                               // prepw Wo
    int idx = b * 256 + tid;
    if (idx < NLAYER * HDIM * HDIM){
      int mat = idx >> 14, rem = idx & 16383;
      int n = rem >> 7, k = rem & 127;
      float w = Wo[(mat << 14) + k * HDIM + n];
      unsigned short hi = f2bf(w);
      WoHiT[idx] = hi;
      WoLoT[idx] = f2bf(w - bf2f(hi));
    }
    return;
  }
  b -= B2;
  if (b < B4){                               // ac
    int idx = b * 256 + tid;
    if (idx < NLAYER * HDIM){
      int l = idx >> 7, f = idx & 127;
      float av = 0.f, cv = 0.f;
      for (int g = 0; g < NGAUSS; ++g){
        float we = We[(l * NGAUSS + g) * HDIM + f];
        av += dW[g] * we;
        cv += db[g] * we;
      }
      a[idx] = av;
      c[idx] = cv + be[idx];
    }
    return;
  }
  b -= B4;
  if (b < B5){                               // bounds over sorted batch
    int i = b * 256 + tid;
    if (i >= N) return;
    int bb = batch[i];
    if (i == 0){
      for (int g = 0; g <= bb; ++g) groupOff[g] = 0;
    } else {
      int pb = batch[i - 1];
      for (int g = pb + 1; g <= bb; ++g) groupOff[g] = i;
    }
    if (i == N - 1){
      for (int g = bb + 1; g <= G; ++g) groupOff[g] = N;
    }
  }
}

// 12-MFMA split-precision product: d = X(hi/lo) @ B(hi/lo)
static __device__ __forceinline__ f32x4 mfma12(const bf16x8* ahi, const bf16x8* alo,
                                               const ushortT* bph, const ushortT* bpl){
  bf16x8 bh0 = *(const bf16x8*)(bph);
  bf16x8 bh1 = *(const bf16x8*)(bph + 32);
  bf16x8 bh2 = *(const bf16x8*)(bph + 64);
  bf16x8 bh3 = *(const bf16x8*)(bph + 96);
  bf16x8 bl0 = *(const bf16x8*)(bpl);
  bf16x8 bl1 = *(const bf16x8*)(bpl + 32);
  bf16x8 bl2 = *(const bf16x8*)(bpl + 64);
  bf16x8 bl3 = *(const bf16x8*)(bpl + 96);
  f32x4 d = {0.f, 0.f, 0.f, 0.f};
  d = __builtin_amdgcn_mfma_f32_16x16x32_bf16(ahi[0], bh0, d, 0, 0, 0);
  d = __builtin_amdgcn_mfma_f32_16x16x32_bf16(ahi[1], bh1, d, 0, 0, 0);
  d = __builtin_amdgcn_mfma_f32_16x16x32_bf16(ahi[2], bh2, d, 0, 0, 0);
  d = __builtin_amdgcn_mfma_f32_16x16x32_bf16(ahi[3], bh3, d, 0, 0, 0);
  d = __builtin_amdgcn_mfma_f32_16x16x32_bf16(ahi[0], bl0, d, 0, 0, 0);
  d = __builtin_amdgcn_mfma_f32_16x16x32_bf16(ahi[1], bl1, d, 0, 0, 0);
  d = __builtin_amdgcn_mfma_f32_16x16x32_bf16(ahi[2], bl2, d, 0, 0, 0);
  d = __builtin_amdgcn_mfma_f32_16x16x32_bf16(ahi[3], bl3, d, 0, 0, 0);
  d = __builtin_amdgcn_mfma_f32_16x16x32_bf16(alo[0], bh0, d, 0, 0, 0);
  d = __builtin_amdgcn_mfma_f32_16x16x32_bf16(alo[1], bh1, d, 0, 0, 0);
  d = __builtin_amdgcn_mfma_f32_16x16x32_bf16(alo[2], bh2, d, 0, 0, 0);
  d = __builtin_amdgcn_mfma_f32_16x16x32_bf16(alo[3], bh3, d, 0, 0, 0);
  return d;
}

// ---------------- initial GEMM: h0 = v0 @ Wn[0], bf16-hi output ----------------
__global__ __launch_bounds__(256, 4)
void k_gemm0(const ushortT* __restrict__ Xhi, const ushortT* __restrict__ Xlo,
             const ushortT* __restrict__ WhiT, const ushortT* __restrict__ WloT,
             ushortT* __restrict__ outHi, int N){
  int tid = threadIdx.x;
  int wave = tid >> 6, lane = tid & 63;
  int m = lane & 15, quad = lane >> 4;
  int ntiles = (N + 15) >> 4;
  int tile = blockIdx.x * 4 + wave;
  if (tile >= ntiles) return;
  int rowBase = tile << 4;
  int row = rowBase + m; if (row >= N) row = N - 1;

  bf16x8 ahi[4], alo[4];
  #pragma unroll
  for (int kk = 0; kk < 4; ++kk){
    ahi[kk] = *(const bf16x8*)(Xhi + ((size_t)row << 7) + kk*32 + quad*8);
    alo[kk] = *(const bf16x8*)(Xlo + ((size_t)row << 7) + kk*32 + quad*8);
  }
  #pragma unroll
  for (int ct = 0; ct < 8; ++ct){
    int ncol = ct * 16 + m;
    f32x4 d = mfma12(ahi, alo, WhiT + ((size_t)ncol << 7) + quad*8,
                               WloT + ((size_t)ncol << 7) + quad*8);
    #pragma unroll
    for (int r = 0; r < 4; ++r){
      int orow = rowBase + quad*4 + r;
      if (orow < N) outHi[((size_t)orow << 7) + ncol] = f2bf(d[r]);
    }
  }
}

// ---------------- edge aggregation: one wave per node, half-wave edge split ----
// Lanes 0-31 take even edges, 32-63 odd edges; each lane gathers 4 features
// (dwordx2). One gather instruction covers 2 edges (2 x 256B segments).
__global__ __launch_bounds__(256, 8)
void k_agg2(const ushortT* __restrict__ h, const int* __restrict__ offsets,
            const int2* __restrict__ cd, const float* __restrict__ a,
            const float* __restrict__ c,
            ushortT* __restrict__ aggHi, ushortT* __restrict__ aggLo, int N){
  int node = blockIdx.x * 4 + (threadIdx.x >> 6);
  if (node >= N) return;
  int lane = threadIdx.x & 63;
  int half = lane >> 5;                 // 0: even edges, 1: odd edges
  int fl = (lane & 31) * 4;             // this lane's 4 features
  float4 av = *(const float4*)(a + fl);
  float4 cv = *(const float4*)(c + fl);
  int s = offsets[node], e = offsets[node + 1];
  float acc0 = 0.f, acc1 = 0.f, acc2 = 0.f, acc3 = 0.f;
  int j = s;
  // main: 8 edges per iteration (4 per half-wave), 4 gathers in flight
  for (; j + 8 <= e; j += 8){
    int2 q[4]; uint2 p[4];
    #pragma unroll
    for (int i = 0; i < 4; ++i) q[i] = cd[j + 2*i + half];
    #pragma unroll
    for (int i = 0; i < 4; ++i)
      p[i] = *(const uint2*)(h + ((size_t)q[i].x << 7) + fl);
    #pragma unroll
    for (int i = 0; i < 4; ++i){
      float dd = __int_as_float(q[i].y);
      float w0 = fmaf(dd, av.x, cv.x);
      float w1 = fmaf(dd, av.y, cv.y);
      float w2 = fmaf(dd, av.z, cv.z);
      float w3 = fmaf(dd, av.w, cv.w);
      acc0 = fmaf(bf2f((ushortT)p[i].x),         w0, acc0);
      acc1 = fmaf(bf2f((ushortT)(p[i].x >> 16)), w1, acc1);
      acc2 = fmaf(bf2f((ushortT)p[i].y),         w2, acc2);
      acc3 = fmaf(bf2f((ushortT)(p[i].y >> 16)), w3, acc3);
    }
  }
  // remainder: 2 edges at a time with per-half validity
  for (; j < e; j += 2){
    int myj = j + half;
    if (myj < e){
      int2 q = cd[myj];
      uint2 p = *(const uint2*)(h + ((size_t)q.x << 7) + fl);
      float dd = __int_as_float(q.y);
      acc0 = fmaf(bf2f((ushortT)p.x),         fmaf(dd, av.x, cv.x), acc0);
      acc1 = fmaf(bf2f((ushortT)(p.x >> 16)), fmaf(dd, av.y, cv.y), acc1);
      acc2 = fmaf(bf2f((ushortT)p.y),         fmaf(dd, av.z, cv.z), acc2);
      acc3 = fmaf(bf2f((ushortT)(p.y >> 16)), fmaf(dd, av.w, cv.w), acc3);
    }
  }
  // combine halves: lanes 0-31 += lanes 32-63
  acc0 += __shfl_down(acc0, 32, 64);
  acc1 += __shfl_down(acc1, 32, 64);
  acc2 += __shfl_down(acc2, 32, 64);
  acc3 += __shfl_down(acc3, 32, 64);
  if (half == 0){
    unsigned short h0 = f2bf(acc0), h1 = f2bf(acc1), h2 = f2bf(acc2), h3 = f2bf(acc3);
    unsigned short l0 = f2bf(acc0 - bf2f(h0)), l1 = f2bf(acc1 - bf2f(h1));
    unsigned short l2 = f2bf(acc2 - bf2f(h2)), l3 = f2bf(acc3 - bf2f(h3));
    size_t o = ((size_t)node << 7) + fl;
    uint2 ph, pl;
    ph.x = (unsigned int)h0 | ((unsigned int)h1 << 16);
    ph.y = (unsigned int)h2 | ((unsigned int)h3 << 16);
    pl.x = (unsigned int)l0 | ((unsigned int)l1 << 16);
    pl.y = (unsigned int)l2 | ((unsigned int)l3 << 16);
    *(uint2*)(aggHi + o) = ph;
    *(uint2*)(aggLo + o) = pl;
  }
}

// ---------------- fused GEMM pair: v = ssp(agg@Wo+bo); h' = v@WnNext ----------
// One wave = one 16-row tile, private LDS tile (no barrier). LAST: readout.
template<int LAST>
__global__ __launch_bounds__(256, 3)
void k_fused(const ushortT* __restrict__ aggHi, const ushortT* __restrict__ aggLo,
             const ushortT* __restrict__ WoHiT, const ushortT* __restrict__ WoLoT,
             const float* __restrict__ bo,
             const ushortT* __restrict__ WnHiT, const ushortT* __restrict__ WnLoT,
             ushortT* __restrict__ outH,
             const float* __restrict__ W1, const float* __restrict__ b1,
             const float* __restrict__ W2, const float* __restrict__ b2,
             float* __restrict__ u, int N){
  __shared__ ushortT th[LAST ? 1 : 4 * 16 * TSTR];
  __shared__ ushortT tl[LAST ? 1 : 4 * 16 * TSTR];
  __shared__ float   vf[LAST ? 4 * 16 * VSTR : 1];
  int tid = threadIdx.x;
  int wave = tid >> 6, lane = tid & 63;
  int m = lane & 15, quad = lane >> 4;
  int ntiles = (N + 15) >> 4;
  int tile = blockIdx.x * 4 + wave;
  if (tile >= ntiles) return;
  int rowBase = tile << 4;
  int row = rowBase + m; if (row >= N) row = N - 1;

  bf16x8 ahi[4], alo[4];
  #pragma unroll
  for (int kk = 0; kk < 4; ++kk){
    ahi[kk] = *(const bf16x8*)(aggHi + ((size_t)row << 7) + kk*32 + quad*8);
    alo[kk] = *(const bf16x8*)(aggLo + ((size_t)row << 7) + kk*32 + quad*8);
  }
  #pragma unroll
  for (int ct = 0; ct < 8; ++ct){
    int ncol = ct * 16 + m;
    f32x4 d = mfma12(ahi, alo, WoHiT + ((size_t)ncol << 7) + quad*8,
                               WoLoT + ((size_t)ncol << 7) + quad*8);
    float bb = bo[ncol];
    #pragma unroll
    for (int r = 0; r < 4; ++r){
      float sv = ssp(d[r] + bb);
      if (LAST){
        vf[(wave*16 + quad*4 + r) * VSTR + ncol] = sv;
      } else {
        unsigned short hi = f2bf(sv);
        int idx = wave * 16 * TSTR + (quad*4 + r) * TSTR + ncol;
        th[idx] = hi;
        tl[idx] = f2bf(sv - bf2f(hi));
      }
    }
  }
  if (!LAST){
    // same-wave LDS write->read: compiler orders via lgkmcnt (wave-private tile)
    bf16x8 a2h[4], a2l[4];
    #pragma unroll
    for (int kk = 0; kk < 4; ++kk){
      a2h[kk] = *(const bf16x8*)(&th[wave * 16 * TSTR + m * TSTR + kk*32 + quad*8]);
      a2l[kk] = *(const bf16x8*)(&tl[wave * 16 * TSTR + m * TSTR + kk*32 + quad*8]);
    }
    #pragma unroll
    for (int ct = 0; ct < 8; ++ct){
      int ncol = ct * 16 + m;
      f32x4 d = mfma12(a2h, a2l, WnHiT + ((size_t)ncol << 7) + quad*8,
                                 WnLoT + ((size_t)ncol << 7) + quad*8);
      #pragma unroll
      for (int r = 0; r < 4; ++r){
        int orow = rowBase + quad*4 + r;
        if (orow < N) outH[((size_t)orow << 7) + ncol] = f2bf(d[r]);
      }
    }
  } else {
    // readout: u[node] = ssp(v@W1+b1)@W2 + b2, 16 nodes serial per wave
    #pragma unroll 1
    for (int i = 0; i < 16; ++i){
      int node = rowBase + i;
      if (node >= N) break;
      const float* vrow = &vf[(wave*16 + i) * VSTR];
      float t0 = b1[lane], t1 = 0.f;
      #pragma unroll 8
      for (int k = 0; k < HDIM; k += 2){
        t0 = fmaf(vrow[k],     W1[k * 64 + lane],       t0);
        t1 = fmaf(vrow[k + 1], W1[(k + 1) * 64 + lane], t1);
      }
      float partial = ssp(t0 + t1) * W2[lane];
      #pragma unroll
      for (int off = 32; off > 0; off >>= 1)
        partial += __shfl_down(partial, off, 64);
      if (lane == 0) u[node] = partial + b2[0];
    }
  }
}

// ---------------- group segment sum over sorted batch ----------------
__global__ void k_gsum(const float* __restrict__ u, const int* __restrict__ groupOff,
                       float* __restrict__ out, int G){
  int g = blockIdx.x * 4 + (threadIdx.x >> 6);
  if (g >= G) return;
  int lane = threadIdx.x & 63;
  int s = groupOff[g], e = groupOff[g + 1];
  float acc = 0.f;
  for (int j = s + lane; j < e; j += 64) acc += u[j];
  #pragma unroll
  for (int off = 32; off > 0; off >>= 1)
    acc += __shfl_down(acc, off, 64);
  if (lane == 0) out[g] = acc;
}

extern "C" void kernel_launch(void* const* d_in, const int* in_sizes, int n_in,
                              void* d_out, int out_size, void* d_ws, size_t ws_size,
                              hipStream_t stream){
  const int N = in_sizes[0];
  const int E = in_sizes[3] / 2;
  const int G = out_size;

  const int*   z     = (const int*)d_in[0];
  const float* pos   = (const float*)d_in[1];
  const int*   batch = (const int*)d_in[2];
  const int*   eidx  = (const int*)d_in[3];
  const int*   erow  = eidx;
  const int*   ecol  = eidx + E;
  const float* emb   = (const float*)d_in[4];
  const float* dW    = (const float*)d_in[5];
  const float* db    = (const float*)d_in[6];
  const float* Wn    = (const float*)d_in[7];
  const float* We    = (const float*)d_in[8];
  const float* be    = (const float*)d_in[9];
  const float* Wo    = (const float*)d_in[10];
  const float* bo    = (const float*)d_in[11];
  const float* W1    = (const float*)d_in[12];
  const float* b1    = (const float*)d_in[13];
  const float* W2    = (const float*)d_in[14];
  const float* b2    = (const float*)d_in[15];

  char* ws = (char*)d_ws;
  size_t off = 0;
  auto alloc = [&](size_t bytes) -> char* {
    char* p = ws + off;
    off = (off + bytes + 255) & ~(size_t)255;
    return p;
  };
  int nscanb = (N + 255) / 256;
  int*     counts   = (int*)    alloc((size_t)N * 4);
  int*     offsets  = (int*)    alloc((size_t)(N + 1) * 4);
  int*     cursor   = (int*)    alloc((size_t)N * 4);
  int*     blockSums= (int*)    alloc((size_t)nscanb * 4);
  int2*    csr_cd   = (int2*)   alloc((size_t)E * 8);
  ushortT* h0       = (ushortT*)alloc((size_t)N * HDIM * 2);
  ushortT* h1       = (ushortT*)alloc((size_t)N * HDIM * 2);
  ushortT* vhi      = (ushortT*)alloc((size_t)N * HDIM * 2);
  ushortT* vlo      = (ushortT*)alloc((size_t)N * HDIM * 2);
  ushortT* agghi    = (ushortT*)alloc((size_t)N * HDIM * 2);
  ushortT* agglo    = (ushortT*)alloc((size_t)N * HDIM * 2);
  ushortT* WnHiT    = (ushortT*)alloc((size_t)NLAYER * HDIM * HDIM * 2);
  ushortT* WnLoT    = (ushortT*)alloc((size_t)NLAYER * HDIM * HDIM * 2);
  ushortT* WoHiT    = (ushortT*)alloc((size_t)NLAYER * HDIM * HDIM * 2);
  ushortT* WoLoT    = (ushortT*)alloc((size_t)NLAYER * HDIM * HDIM * 2);
  float*   a        = (float*)  alloc((size_t)NLAYER * HDIM * 4);
  float*   c        = (float*)  alloc((size_t)NLAYER * HDIM * 4);
  float*   u        = (float*)  alloc((size_t)N * 4);
  int*     groupOff = (int*)    alloc((size_t)(G + 1) * 4);

  // merged setup: zero counts + init_v + prepw(Wn) + prepw(Wo) + ac + bounds
  int B0 = (N + 255) / 256;
  int B1 = (N * HDIM + 255) / 256;
  int B2 = (NLAYER * HDIM * HDIM + 255) / 256;
  int B4 = (NLAYER * HDIM + 255) / 256;
  int B5 = (N + 255) / 256;
  k_setup<<<B0 + B1 + 2*B2 + B4 + B5, 256, 0, stream>>>(
      z, emb, vhi, vlo, Wn, WnHiT, WnLoT, Wo, WoHiT, WoLoT,
      dW, db, We, be, a, c, batch, groupOff, counts, N, G, B0, B1, B2, B4, B5);

  k_count<<<(E + 255) / 256, 256, 0, stream>>>(erow, counts, E);
  k_scan1<<<nscanb, 256, 0, stream>>>(counts, blockSums, N);
  k_scan3<<<nscanb, 256, 0, stream>>>(counts, blockSums, offsets, cursor, N, nscanb);
  k_fill<<<(E + 255) / 256, 256, 0, stream>>>(erow, ecol, pos, cursor, csr_cd, E);

  int ntiles = (N + 15) >> 4;
  int gemmGrid = (ntiles + 3) / 4;
  int nodeGrid = (N + 3) / 4;
  k_gemm0<<<gemmGrid, 256, 0, stream>>>(vhi, vlo, WnHiT, WnLoT, h0, N);

  for (int l = 0; l < NLAYER; ++l){
    size_t wo = (size_t)l * HDIM * HDIM;
    const ushortT* hin  = (l & 1) ? h1 : h0;
    ushortT*       hout = (l & 1) ? h0 : h1;
    k_agg2<<<nodeGrid, 256, 0, stream>>>(hin, offsets, csr_cd,
                                         a + l * HDIM, c + l * HDIM, agghi, agglo, N);
    if (l < NLAYER - 1){
      size_t wn = (size_t)(l + 1) * HDIM * HDIM;
      k_fused<0><<<gemmGrid, 256, 0, stream>>>(agghi, agglo, WoHiT + wo, WoLoT + wo,
          bo + (size_t)l * HDIM, WnHiT + wn, WnLoT + wn, hout,
          nullptr, nullptr, nullptr, nullptr, nullptr, N);
    } else {
      k_fused<1><<<gemmGrid, 256, 0, stream>>>(agghi, agglo, WoHiT + wo, WoLoT + wo,
          bo + (size_t)l * HDIM, nullptr, nullptr, nullptr,
          W1, b1, W2, b2, u, N);
    }
  }
  k_gsum<<<(G + 3) / 4, 256, 0, stream>>>(u, groupOff, (float*)d_out, G);
}

// Round 11
// 913.883 us; speedup vs baseline: 1.2375x; 1.1569x over previous
//
#include <hip/hip_runtime.h>
#include <math.h>

#define HDIM 128
#define NGAUSS 50
#define NLAYER 6
#define TSTR 136   // LDS bf16 tile row stride (shorts); %8==0 keeps ds_read_b128 aligned
#define VSTR 132   // LDS f32 tile row stride (floats)

typedef unsigned short ushortT;
typedef __attribute__((ext_vector_type(8))) short bf16x8;
typedef __attribute__((ext_vector_type(4))) float f32x4;

static __device__ __forceinline__ float bf2f(unsigned short u){
  union { unsigned int i; float f; } x; x.i = ((unsigned int)u) << 16; return x.f;
}
static __device__ __forceinline__ unsigned short f2bf(float f){
  union { float f; unsigned int i; } x; x.f = f;
  unsigned int i = x.i;
  unsigned int r = (i + 0x7FFFu + ((i >> 16) & 1u)) >> 16;
  return (unsigned short)r;
}
// softplus(x) - log(2): fast native-exp/log form. Absolute error <1e-7
// (log(1+t) in f32 for t=exp(-|x|) in (0,1]) -- negligible vs bf16 rounding.
static __device__ __forceinline__ float ssp(float x){
  return fmaxf(x, 0.0f) + __logf(1.0f + __expf(-fabsf(x))) - 0.69314718055994530942f;
}

// ---------------- CSR build ----------------
__global__ void k_count(const int* __restrict__ row, int* __restrict__ counts, int E){
  int e = blockIdx.x * 256 + threadIdx.x;
  if (e < E) atomicAdd(&counts[row[e]], 1);
}

__global__ void k_scan1(const int* __restrict__ counts, int* __restrict__ blockSums, int N){
  __shared__ int red[256];
  int tid = threadIdx.x;
  int i = blockIdx.x * 256 + tid;
  red[tid] = (i < N) ? counts[i] : 0;
  __syncthreads();
  #pragma unroll
  for (int off = 128; off > 0; off >>= 1){
    if (tid < off) red[tid] += red[tid + off];
    __syncthreads();
  }
  if (tid == 0) blockSums[blockIdx.x] = red[0];
}

// scan3 with inlined block-sum scan (nb <= 256)
__global__ void k_scan3(const int* __restrict__ counts, const int* __restrict__ blockSums,
                        int* __restrict__ offsets, int* __restrict__ cursor, int N, int nb){
  __shared__ int bs[256];
  __shared__ int s[256];
  int tid = threadIdx.x;
  bs[tid] = (tid < nb) ? blockSums[tid] : 0;
  __syncthreads();
  #pragma unroll
  for (int off = 1; off < 256; off <<= 1){
    int t = (tid >= off) ? bs[tid - off] : 0;
    __syncthreads();
    bs[tid] += t;
    __syncthreads();
  }
  int myOff = (blockIdx.x == 0) ? 0 : bs[blockIdx.x - 1];
  int i = blockIdx.x * 256 + tid;
  int v = (i < N) ? counts[i] : 0;
  s[tid] = v;
  __syncthreads();
  #pragma unroll
  for (int off = 1; off < 256; off <<= 1){
    int t = (tid >= off) ? s[tid - off] : 0;
    __syncthreads();
    s[tid] += t;
    __syncthreads();
  }
  int excl = myOff + s[tid] - v;
  if (i < N){ offsets[i] = excl; cursor[i] = excl; }
  if (i == N - 1) offsets[N] = excl + v;
}

// csr record: (col, dist-bits) packed as int2
__global__ void k_fill(const int* __restrict__ row, const int* __restrict__ col,
                       const float* __restrict__ pos, int* __restrict__ cursor,
                       int2* __restrict__ csr_cd, int E){
  int e = blockIdx.x * 256 + threadIdx.x;
  if (e >= E) return;
  int r = row[e], c = col[e];
  float dx = pos[r*3+0] - pos[c*3+0];
  float dy = pos[r*3+1] - pos[c*3+1];
  float dz = pos[r*3+2] - pos[c*3+2];
  float d = sqrtf(dx*dx + dy*dy + dz*dz);
  int slot = atomicAdd(&cursor[r], 1);
  csr_cd[slot] = make_int2(c, __float_as_int(d));
}

// ---------------- merged elementwise setup ----------------
// ranges: [zero counts][init_v][prepw Wn][prepw Wo][ac][bounds]
__global__ void k_setup(const int* __restrict__ z, const float* __restrict__ emb,
                        ushortT* __restrict__ vhi, ushortT* __restrict__ vlo,
                        const float* __restrict__ Wn, ushortT* __restrict__ WnHiT,
                        ushortT* __restrict__ WnLoT,
                        const float* __restrict__ Wo, ushortT* __restrict__ WoHiT,
                        ushortT* __restrict__ WoLoT,
                        const float* __restrict__ dW, const float* __restrict__ db,
                        const float* __restrict__ We, const float* __restrict__ be,
                        float* __restrict__ a, float* __restrict__ c,
                        const int* __restrict__ batch, int* __restrict__ groupOff,
                        int* __restrict__ counts,
                        int N, int G, int B0, int B1, int B2, int B4, int B5){
  int b = blockIdx.x;
  int tid = threadIdx.x;
  if (b < B0){                               // zero counts
    int i = b * 256 + tid;
    if (i < N) counts[i] = 0;
    return;
  }
  b -= B0;
  if (b < B1){                               // init_v: split emb[z] hi/lo
    int idx = b * 256 + tid;
    if (idx < N * HDIM){
      int n = idx >> 7, f = idx & 127;
      float w = emb[z[n] * HDIM + f];
      unsigned short hi = f2bf(w);
      vhi[idx] = hi;
      vlo[idx] = f2bf(w - bf2f(hi));
    }
    return;
  }
  b -= B1;
  if (b < B2){                               // prepw Wn
    int idx = b * 256 + tid;
    if (idx < NLAYER * HDIM * HDIM){
      int mat = idx >> 14, rem = idx & 16383;
      int n = rem >> 7, k = rem & 127;
      float w = Wn[(mat << 14) + k * HDIM + n];
      unsigned short hi = f2bf(w);
      WnHiT[idx] = hi;
      WnLoT[idx] = f2bf(w - bf2f(hi));
    }
    return;
  }
  b -= B2;
  if (b < B2){                               // prepw Wo
    int idx = b * 256 + tid;
    if (idx < NLAYER * HDIM * HDIM){
      int mat = idx >> 14, rem = idx & 16383;
      int n = rem >> 7, k = rem & 127;
      float w = Wo[(mat << 14) + k * HDIM + n];
      unsigned short hi = f2bf(w);
      WoHiT[idx] = hi;
      WoLoT[idx] = f2bf(w - bf2f(hi));
    }
    return;
  }
  b -= B2;
  if (b < B4){                               // ac
    int idx = b * 256 + tid;
    if (idx < NLAYER * HDIM){
      int l = idx >> 7, f = idx & 127;
      float av = 0.f, cv = 0.f;
      for (int g = 0; g < NGAUSS; ++g){
        float we = We[(l * NGAUSS + g) * HDIM + f];
        av += dW[g] * we;
        cv += db[g] * we;
      }
      a[idx] = av;
      c[idx] = cv + be[idx];
    }
    return;
  }
  b -= B4;
  if (b < B5){                               // bounds over sorted batch
    int i = b * 256 + tid;
    if (i >= N) return;
    int bb = batch[i];
    if (i == 0){
      for (int g = 0; g <= bb; ++g) groupOff[g] = 0;
    } else {
      int pb = batch[i - 1];
      for (int g = pb + 1; g <= bb; ++g) groupOff[g] = i;
    }
    if (i == N - 1){
      for (int g = bb + 1; g <= G; ++g) groupOff[g] = N;
    }
  }
}

// 12-MFMA split-precision product with preloaded B registers
static __device__ __forceinline__ f32x4 mfma12r(const bf16x8* ahi, const bf16x8* alo,
                                                const bf16x8* bh, const bf16x8* bl){
  f32x4 d = {0.f, 0.f, 0.f, 0.f};
  d = __builtin_amdgcn_mfma_f32_16x16x32_bf16(ahi[0], bh[0], d, 0, 0, 0);
  d = __builtin_amdgcn_mfma_f32_16x16x32_bf16(ahi[1], bh[1], d, 0, 0, 0);
  d = __builtin_amdgcn_mfma_f32_16x16x32_bf16(ahi[2], bh[2], d, 0, 0, 0);
  d = __builtin_amdgcn_mfma_f32_16x16x32_bf16(ahi[3], bh[3], d, 0, 0, 0);
  d = __builtin_amdgcn_mfma_f32_16x16x32_bf16(ahi[0], bl[0], d, 0, 0, 0);
  d = __builtin_amdgcn_mfma_f32_16x16x32_bf16(ahi[1], bl[1], d, 0, 0, 0);
  d = __builtin_amdgcn_mfma_f32_16x16x32_bf16(ahi[2], bl[2], d, 0, 0, 0);
  d = __builtin_amdgcn_mfma_f32_16x16x32_bf16(ahi[3], bl[3], d, 0, 0, 0);
  d = __builtin_amdgcn_mfma_f32_16x16x32_bf16(alo[0], bh[0], d, 0, 0, 0);
  d = __builtin_amdgcn_mfma_f32_16x16x32_bf16(alo[1], bh[1], d, 0, 0, 0);
  d = __builtin_amdgcn_mfma_f32_16x16x32_bf16(alo[2], bh[2], d, 0, 0, 0);
  d = __builtin_amdgcn_mfma_f32_16x16x32_bf16(alo[3], bh[3], d, 0, 0, 0);
  return d;
}

// ---------------- initial GEMM: h0 = v0 @ Wn[0]; 2 row-tiles per wave ----------
__global__ __launch_bounds__(128, 2)
void k_gemm0(const ushortT* __restrict__ Xhi, const ushortT* __restrict__ Xlo,
             const ushortT* __restrict__ WhiT, const ushortT* __restrict__ WloT,
             ushortT* __restrict__ outHi, int N){
  int tid = threadIdx.x;
  int wave = tid >> 6, lane = tid & 63;
  int m = lane & 15, quad = lane >> 4;
  int ntiles = (N + 15) >> 4;
  int t0 = (blockIdx.x * 2 + wave) * 2;
  if (t0 >= ntiles) return;

  bf16x8 ahi[2][4], alo[2][4];
  #pragma unroll
  for (int rt = 0; rt < 2; ++rt){
    int row = (t0 + rt) * 16 + m; if (row >= N) row = N - 1;
    #pragma unroll
    for (int kk = 0; kk < 4; ++kk){
      ahi[rt][kk] = *(const bf16x8*)(Xhi + ((size_t)row << 7) + kk*32 + quad*8);
      alo[rt][kk] = *(const bf16x8*)(Xlo + ((size_t)row << 7) + kk*32 + quad*8);
    }
  }
  #pragma unroll
  for (int ct = 0; ct < 8; ++ct){
    int ncol = ct * 16 + m;
    const ushortT* bph = WhiT + ((size_t)ncol << 7) + quad*8;
    const ushortT* bpl = WloT + ((size_t)ncol << 7) + quad*8;
    bf16x8 bh[4], bl[4];
    #pragma unroll
    for (int kk = 0; kk < 4; ++kk){
      bh[kk] = *(const bf16x8*)(bph + kk*32);
      bl[kk] = *(const bf16x8*)(bpl + kk*32);
    }
    #pragma unroll
    for (int rt = 0; rt < 2; ++rt){
      f32x4 d = mfma12r(ahi[rt], alo[rt], bh, bl);
      #pragma unroll
      for (int r = 0; r < 4; ++r){
        int orow = (t0 + rt) * 16 + quad*4 + r;
        if (orow < N) outHi[((size_t)orow << 7) + ncol] = f2bf(d[r]);
      }
    }
  }
}

// ---------------- edge aggregation: one wave per node, half-wave edge split ----
__global__ __launch_bounds__(256, 8)
void k_agg2(const ushortT* __restrict__ h, const int* __restrict__ offsets,
            const int2* __restrict__ cd, const float* __restrict__ a,
            const float* __restrict__ c,
            ushortT* __restrict__ aggHi, ushortT* __restrict__ aggLo, int N){
  int node = blockIdx.x * 4 + (threadIdx.x >> 6);
  if (node >= N) return;
  int lane = threadIdx.x & 63;
  int half = lane >> 5;                 // 0: even edges, 1: odd edges
  int fl = (lane & 31) * 4;             // this lane's 4 features
  float4 av = *(const float4*)(a + fl);
  float4 cv = *(const float4*)(c + fl);
  int s = offsets[node], e = offsets[node + 1];
  float acc0 = 0.f, acc1 = 0.f, acc2 = 0.f, acc3 = 0.f;
  int j = s;
  for (; j + 8 <= e; j += 8){
    int2 q[4]; uint2 p[4];
    #pragma unroll
    for (int i = 0; i < 4; ++i) q[i] = cd[j + 2*i + half];
    #pragma unroll
    for (int i = 0; i < 4; ++i)
      p[i] = *(const uint2*)(h + ((size_t)q[i].x << 7) + fl);
    #pragma unroll
    for (int i = 0; i < 4; ++i){
      float dd = __int_as_float(q[i].y);
      float w0 = fmaf(dd, av.x, cv.x);
      float w1 = fmaf(dd, av.y, cv.y);
      float w2 = fmaf(dd, av.z, cv.z);
      float w3 = fmaf(dd, av.w, cv.w);
      acc0 = fmaf(bf2f((ushortT)p[i].x),         w0, acc0);
      acc1 = fmaf(bf2f((ushortT)(p[i].x >> 16)), w1, acc1);
      acc2 = fmaf(bf2f((ushortT)p[i].y),         w2, acc2);
      acc3 = fmaf(bf2f((ushortT)(p[i].y >> 16)), w3, acc3);
    }
  }
  for (; j < e; j += 2){
    int myj = j + half;
    if (myj < e){
      int2 q = cd[myj];
      uint2 p = *(const uint2*)(h + ((size_t)q.x << 7) + fl);
      float dd = __int_as_float(q.y);
      acc0 = fmaf(bf2f((ushortT)p.x),         fmaf(dd, av.x, cv.x), acc0);
      acc1 = fmaf(bf2f((ushortT)(p.x >> 16)), fmaf(dd, av.y, cv.y), acc1);
      acc2 = fmaf(bf2f((ushortT)p.y),         fmaf(dd, av.z, cv.z), acc2);
      acc3 = fmaf(bf2f((ushortT)(p.y >> 16)), fmaf(dd, av.w, cv.w), acc3);
    }
  }
  acc0 += __shfl_down(acc0, 32, 64);
  acc1 += __shfl_down(acc1, 32, 64);
  acc2 += __shfl_down(acc2, 32, 64);
  acc3 += __shfl_down(acc3, 32, 64);
  if (half == 0){
    unsigned short h0 = f2bf(acc0), h1 = f2bf(acc1), h2 = f2bf(acc2), h3 = f2bf(acc3);
    unsigned short l0 = f2bf(acc0 - bf2f(h0)), l1 = f2bf(acc1 - bf2f(h1));
    unsigned short l2 = f2bf(acc2 - bf2f(h2)), l3 = f2bf(acc3 - bf2f(h3));
    size_t o = ((size_t)node << 7) + fl;
    uint2 ph, pl;
    ph.x = (unsigned int)h0 | ((unsigned int)h1 << 16);
    ph.y = (unsigned int)h2 | ((unsigned int)h3 << 16);
    pl.x = (unsigned int)l0 | ((unsigned int)l1 << 16);
    pl.y = (unsigned int)l2 | ((unsigned int)l3 << 16);
    *(uint2*)(aggHi + o) = ph;
    *(uint2*)(aggLo + o) = pl;
  }
}

// ---------------- fused GEMM pair: v = ssp(agg@Wo+bo); h' = v@WnNext ----------
// 128-thread blocks, 2 waves; each wave owns 2 row-tiles (32 rows) + a private
// LDS tile (no barrier). B fragments loaded once per column-tile, reused for
// both row-tiles -> 2 independent MFMA chains + halved B traffic.
template<int LAST>
__global__ __launch_bounds__(128, 2)
void k_fused(const ushortT* __restrict__ aggHi, const ushortT* __restrict__ aggLo,
             const ushortT* __restrict__ WoHiT, const ushortT* __restrict__ WoLoT,
             const float* __restrict__ bo,
             const ushortT* __restrict__ WnHiT, const ushortT* __restrict__ WnLoT,
             ushortT* __restrict__ outH,
             const float* __restrict__ W1, const float* __restrict__ b1,
             const float* __restrict__ W2, const float* __restrict__ b2,
             float* __restrict__ u, int N){
  __shared__ ushortT th[LAST ? 1 : 2 * 32 * TSTR];
  __shared__ ushortT tl[LAST ? 1 : 2 * 32 * TSTR];
  __shared__ float   vf[LAST ? 2 * 32 * VSTR : 1];
  int tid = threadIdx.x;
  int wave = tid >> 6, lane = tid & 63;
  int m = lane & 15, quad = lane >> 4;
  int ntiles = (N + 15) >> 4;
  int t0 = (blockIdx.x * 2 + wave) * 2;
  if (t0 >= ntiles) return;
  int lbase = wave * 32 * TSTR;

  bf16x8 ahi[2][4], alo[2][4];
  #pragma unroll
  for (int rt = 0; rt < 2; ++rt){
    int row = (t0 + rt) * 16 + m; if (row >= N) row = N - 1;
    #pragma unroll
    for (int kk = 0; kk < 4; ++kk){
      ahi[rt][kk] = *(const bf16x8*)(aggHi + ((size_t)row << 7) + kk*32 + quad*8);
      alo[rt][kk] = *(const bf16x8*)(aggLo + ((size_t)row << 7) + kk*32 + quad*8);
    }
  }
  // GEMM1: v = ssp(agg @ Wo + bo), into LDS (hi/lo) or f32 LDS (LAST)
  #pragma unroll
  for (int ct = 0; ct < 8; ++ct){
    int ncol = ct * 16 + m;
    const ushortT* bph = WoHiT + ((size_t)ncol << 7) + quad*8;
    const ushortT* bpl = WoLoT + ((size_t)ncol << 7) + quad*8;
    bf16x8 bh[4], bl[4];
    #pragma unroll
    for (int kk = 0; kk < 4; ++kk){
      bh[kk] = *(const bf16x8*)(bph + kk*32);
      bl[kk] = *(const bf16x8*)(bpl + kk*32);
    }
    float bb = bo[ncol];
    #pragma unroll
    for (int rt = 0; rt < 2; ++rt){
      f32x4 d = mfma12r(ahi[rt], alo[rt], bh, bl);
      #pragma unroll
      for (int r = 0; r < 4; ++r){
        float sv = ssp(d[r] + bb);
        if (LAST){
          vf[(wave*32 + rt*16 + quad*4 + r) * VSTR + ncol] = sv;
        } else {
          unsigned short hi = f2bf(sv);
          int idx = lbase + (rt*16 + quad*4 + r) * TSTR + ncol;
          th[idx] = hi;
          tl[idx] = f2bf(sv - bf2f(hi));
        }
      }
    }
  }
  if (!LAST){
    // GEMM2: h' = v @ WnNext (same-wave LDS round trip, lgkmcnt-ordered)
    bf16x8 a2h[2][4], a2l[2][4];
    #pragma unroll
    for (int rt = 0; rt < 2; ++rt){
      #pragma unroll
      for (int kk = 0; kk < 4; ++kk){
        a2h[rt][kk] = *(const bf16x8*)(&th[lbase + (rt*16 + m) * TSTR + kk*32 + quad*8]);
        a2l[rt][kk] = *(const bf16x8*)(&tl[lbase + (rt*16 + m) * TSTR + kk*32 + quad*8]);
      }
    }
    #pragma unroll
    for (int ct = 0; ct < 8; ++ct){
      int ncol = ct * 16 + m;
      const ushortT* bph = WnHiT + ((size_t)ncol << 7) + quad*8;
      const ushortT* bpl = WnLoT + ((size_t)ncol << 7) + quad*8;
      bf16x8 bh[4], bl[4];
      #pragma unroll
      for (int kk = 0; kk < 4; ++kk){
        bh[kk] = *(const bf16x8*)(bph + kk*32);
        bl[kk] = *(const bf16x8*)(bpl + kk*32);
      }
      #pragma unroll
      for (int rt = 0; rt < 2; ++rt){
        f32x4 d = mfma12r(a2h[rt], a2l[rt], bh, bl);
        #pragma unroll
        for (int r = 0; r < 4; ++r){
          int orow = (t0 + rt) * 16 + quad*4 + r;
          if (orow < N) outH[((size_t)orow << 7) + ncol] = f2bf(d[r]);
        }
      }
    }
  } else {
    // readout: u[node] = ssp(v@W1+b1)@W2 + b2, 32 nodes serial per wave
    #pragma unroll 1
    for (int i = 0; i < 32; ++i){
      int node = t0 * 16 + i;
      if (node >= N) break;
      const float* vrow = &vf[(wave*32 + i) * VSTR];
      float tt0 = b1[lane], tt1 = 0.f;
      #pragma unroll 8
      for (int k = 0; k < HDIM; k += 2){
        tt0 = fmaf(vrow[k],     W1[k * 64 + lane],       tt0);
        tt1 = fmaf(vrow[k + 1], W1[(k + 1) * 64 + lane], tt1);
      }
      float partial = ssp(tt0 + tt1) * W2[lane];
      #pragma unroll
      for (int off = 32; off > 0; off >>= 1)
        partial += __shfl_down(partial, off, 64);
      if (lane == 0) u[node] = partial + b2[0];
    }
  }
}

// ---------------- group segment sum over sorted batch ----------------
__global__ void k_gsum(const float* __restrict__ u, const int* __restrict__ groupOff,
                       float* __restrict__ out, int G){
  int g = blockIdx.x * 4 + (threadIdx.x >> 6);
  if (g >= G) return;
  int lane = threadIdx.x & 63;
  int s = groupOff[g], e = groupOff[g + 1];
  float acc = 0.f;
  for (int j = s + lane; j < e; j += 64) acc += u[j];
  #pragma unroll
  for (int off = 32; off > 0; off >>= 1)
    acc += __shfl_down(acc, off, 64);
  if (lane == 0) out[g] = acc;
}

extern "C" void kernel_launch(void* const* d_in, const int* in_sizes, int n_in,
                              void* d_out, int out_size, void* d_ws, size_t ws_size,
                              hipStream_t stream){
  const int N = in_sizes[0];
  const int E = in_sizes[3] / 2;
  const int G = out_size;

  const int*   z     = (const int*)d_in[0];
  const float* pos   = (const float*)d_in[1];
  const int*   batch = (const int*)d_in[2];
  const int*   eidx  = (const int*)d_in[3];
  const int*   erow  = eidx;
  const int*   ecol  = eidx + E;
  const float* emb   = (const float*)d_in[4];
  const float* dW    = (const float*)d_in[5];
  const float* db    = (const float*)d_in[6];
  const float* Wn    = (const float*)d_in[7];
  const float* We    = (const float*)d_in[8];
  const float* be    = (const float*)d_in[9];
  const float* Wo    = (const float*)d_in[10];
  const float* bo    = (const float*)d_in[11];
  const float* W1    = (const float*)d_in[12];
  const float* b1    = (const float*)d_in[13];
  const float* W2    = (const float*)d_in[14];
  const float* b2    = (const float*)d_in[15];

  char* ws = (char*)d_ws;
  size_t off = 0;
  auto alloc = [&](size_t bytes) -> char* {
    char* p = ws + off;
    off = (off + bytes + 255) & ~(size_t)255;
    return p;
  };
  int nscanb = (N + 255) / 256;
  int*     counts   = (int*)    alloc((size_t)N * 4);
  int*     offsets  = (int*)    alloc((size_t)(N + 1) * 4);
  int*     cursor   = (int*)    alloc((size_t)N * 4);
  int*     blockSums= (int*)    alloc((size_t)nscanb * 4);
  int2*    csr_cd   = (int2*)   alloc((size_t)E * 8);
  ushortT* h0       = (ushortT*)alloc((size_t)N * HDIM * 2);
  ushortT* h1       = (ushortT*)alloc((size_t)N * HDIM * 2);
  ushortT* vhi      = (ushortT*)alloc((size_t)N * HDIM * 2);
  ushortT* vlo      = (ushortT*)alloc((size_t)N * HDIM * 2);
  ushortT* agghi    = (ushortT*)alloc((size_t)N * HDIM * 2);
  ushortT* agglo    = (ushortT*)alloc((size_t)N * HDIM * 2);
  ushortT* WnHiT    = (ushortT*)alloc((size_t)NLAYER * HDIM * HDIM * 2);
  ushortT* WnLoT    = (ushortT*)alloc((size_t)NLAYER * HDIM * HDIM * 2);
  ushortT* WoHiT    = (ushortT*)alloc((size_t)NLAYER * HDIM * HDIM * 2);
  ushortT* WoLoT    = (ushortT*)alloc((size_t)NLAYER * HDIM * HDIM * 2);
  float*   a        = (float*)  alloc((size_t)NLAYER * HDIM * 4);
  float*   c        = (float*)  alloc((size_t)NLAYER * HDIM * 4);
  float*   u        = (float*)  alloc((size_t)N * 4);
  int*     groupOff = (int*)    alloc((size_t)(G + 1) * 4);

  // merged setup: zero counts + init_v + prepw(Wn) + prepw(Wo) + ac + bounds
  int B0 = (N + 255) / 256;
  int B1 = (N * HDIM + 255) / 256;
  int B2 = (NLAYER * HDIM * HDIM + 255) / 256;
  int B4 = (NLAYER * HDIM + 255) / 256;
  int B5 = (N + 255) / 256;
  k_setup<<<B0 + B1 + 2*B2 + B4 + B5, 256, 0, stream>>>(
      z, emb, vhi, vlo, Wn, WnHiT, WnLoT, Wo, WoHiT, WoLoT,
      dW, db, We, be, a, c, batch, groupOff, counts, N, G, B0, B1, B2, B4, B5);

  k_count<<<(E + 255) / 256, 256, 0, stream>>>(erow, counts, E);
  k_scan1<<<nscanb, 256, 0, stream>>>(counts, blockSums, N);
  k_scan3<<<nscanb, 256, 0, stream>>>(counts, blockSums, offsets, cursor, N, nscanb);
  k_fill<<<(E + 255) / 256, 256, 0, stream>>>(erow, ecol, pos, cursor, csr_cd, E);

  int ntiles = (N + 15) >> 4;
  int nwj = (ntiles + 1) / 2;            // wave-jobs (2 tiles each)
  int pairGrid = (nwj + 1) / 2;          // 2 waves per 128-thread block
  int nodeGrid = (N + 3) / 4;
  k_gemm0<<<pairGrid, 128, 0, stream>>>(vhi, vlo, WnHiT, WnLoT, h0, N);

  for (int l = 0; l < NLAYER; ++l){
    size_t wo = (size_t)l * HDIM * HDIM;
    const ushortT* hin  = (l & 1) ? h1 : h0;
    ushortT*       hout = (l & 1) ? h0 : h1;
    k_agg2<<<nodeGrid, 256, 0, stream>>>(hin, offsets, csr_cd,
                                         a + l * HDIM, c + l * HDIM, agghi, agglo, N);
    if (l < NLAYER - 1){
      size_t wn = (size_t)(l + 1) * HDIM * HDIM;
      k_fused<0><<<pairGrid, 128, 0, stream>>>(agghi, agglo, WoHiT + wo, WoLoT + wo,
          bo + (size_t)l * HDIM, WnHiT + wn, WnLoT + wn, hout,
          nullptr, nullptr, nullptr, nullptr, nullptr, N);
    } else {
      k_fused<1><<<pairGrid, 128, 0, stream>>>(agghi, agglo, WoHiT + wo, WoLoT + wo,
          bo + (size_t)l * HDIM, nullptr, nullptr, nullptr,
          W1, b1, W2, b2, u, N);
    }
  }
  k_gsum<<<(G + 3) / 4, 256, 0, stream>>>(u, groupOff, (float*)d_out, G);
}